// Round 18
// baseline (206.538 us; speedup 1.0000x reference)
//
#include <hip/hip_runtime.h>
#include <cstddef>
#include <math.h>

#define S_LEN  2048
#define HID_C  1024
#define NHEADS 16
#define HDIM   64

typedef __attribute__((ext_vector_type(8))) short bf16x8;
typedef __attribute__((ext_vector_type(4))) float f32x4;
typedef __attribute__((ext_vector_type(16))) float f32x16;
typedef unsigned short ushort_t;

#define LOG2E 1.44269504088896f

__device__ __forceinline__ unsigned short f32_to_bf16_rn(float f) {
    unsigned int u = __float_as_uint(f);
    return (unsigned short)((u + 0x8000u) >> 16);
}

// raw hardware exp2: one v_exp_f32 (vs exp2f's multi-instruction ocml call)
__device__ __forceinline__ float fexp2(float x) {
    float r;
    asm("v_exp_f32 %0, %1" : "=v"(r) : "v"(x));
    return r;
}

// direct global->LDS 16B copy (lds dest = wave-uniform base + lane*16;
// global src may be per-lane)
__device__ __forceinline__ void gload16(const ushort_t* g, ushort_t* l) {
    __builtin_amdgcn_global_load_lds(
        (const __attribute__((address_space(1))) void*)g,
        (__attribute__((address_space(3))) void*)l, 16, 0, 0);
}

// balanced tree reductions over f32x16 (depth 5; max3-fusable)
__device__ __forceinline__ float tmax16(const f32x16& v) {
    float a0 = fmaxf(v[0], v[1]),   a1 = fmaxf(v[2], v[3]);
    float a2 = fmaxf(v[4], v[5]),   a3 = fmaxf(v[6], v[7]);
    float a4 = fmaxf(v[8], v[9]),   a5 = fmaxf(v[10], v[11]);
    float a6 = fmaxf(v[12], v[13]), a7 = fmaxf(v[14], v[15]);
    float b0 = fmaxf(a0, a1), b1 = fmaxf(a2, a3);
    float b2 = fmaxf(a4, a5), b3 = fmaxf(a6, a7);
    return fmaxf(fmaxf(b0, b1), fmaxf(b2, b3));
}
__device__ __forceinline__ float tsum16(const f32x16& v) {
    float a0 = v[0] + v[1],   a1 = v[2] + v[3];
    float a2 = v[4] + v[5],   a3 = v[6] + v[7];
    float a4 = v[8] + v[9],   a5 = v[10] + v[11];
    float a6 = v[12] + v[13], a7 = v[14] + v[15];
    float b0 = a0 + a1, b1 = a2 + a3, b2 = a4 + a5, b3 = a6 + a7;
    return (b0 + b1) + (b2 + b3);
}

// ---------------------------------------------------------------------------
// scan: order-preserving compaction of valid key indices per batch.
// ---------------------------------------------------------------------------
__global__ void scan_mask(const int* __restrict__ mask, int* __restrict__ cidx,
                          int* __restrict__ nvalid, int* __restrict__ npads) {
    const int b = blockIdx.x;
    const int lane = threadIdx.x;           // blockDim.x == 64
    int base = 0;
    for (int i = 0; i < S_LEN / 64; ++i) {
        const int s = i * 64 + lane;
        const int v = mask[b * S_LEN + s];
        const unsigned long long bal = __ballot(v != 0);
        const int pre = __popcll(bal & ((1ull << lane) - 1ull));
        if (v) cidx[b * S_LEN + base + pre] = s;
        base += (int)__popcll(bal);
    }
    if (lane == 0) { nvalid[b] = base; npads[b] = (base + 63) & ~63; }
}

// ---------------------------------------------------------------------------
// fused prep + gather (unchanged from R17)
// ---------------------------------------------------------------------------
#define CONVB 12288

__global__ void prep_gather(
    const float* __restrict__ query,
    const float* __restrict__ Wq, const float* __restrict__ Wk,
    const float* __restrict__ Wo, const float* __restrict__ Wv,
    const float* __restrict__ key, const float* __restrict__ value,
    const int* __restrict__ cidx, const int* __restrict__ nvalid,
    ushort_t* __restrict__ Qbf, ushort_t* __restrict__ Wqb,
    ushort_t* __restrict__ Wkb, ushort_t* __restrict__ Wob,
    ushort_t* __restrict__ Wvb,
    ushort_t* __restrict__ Kc, ushort_t* __restrict__ Vc,
    float* __restrict__ Mbc)
{
    if (blockIdx.x < CONVB) {
        const unsigned SEG = 4u * S_LEN * HID_C;
        const unsigned NW = HID_C * HID_C;
        unsigned i = (blockIdx.x * 256u + threadIdx.x) * 4u;
        const float* src; ushort_t* dst;
        if (i < SEG) { src = query; dst = Qbf; }
        else {
            i -= SEG;
            if (i < NW) { src = Wq; dst = Wqb; }
            else { i -= NW;
                if (i < NW) { src = Wk; dst = Wkb; }
                else { i -= NW;
                    if (i < NW) { src = Wo; dst = Wob; }
                    else { i -= NW; if (i >= NW) return; src = Wv; dst = Wvb; }
                }
            }
        }
        float4 v = *reinterpret_cast<const float4*>(src + i);
        uint2 p;
        p.x = ((unsigned)f32_to_bf16_rn(v.y) << 16) | f32_to_bf16_rn(v.x);
        p.y = ((unsigned)f32_to_bf16_rn(v.w) << 16) | f32_to_bf16_rn(v.z);
        *reinterpret_cast<uint2*>(dst + i) = p;
    } else {
        const int r = blockIdx.x - CONVB;       // 0..8191 compact row
        const int b = r >> 11, j = r & 2047;
        const int tid = threadIdx.x;
        const int nv = nvalid[b];
        if (tid == 0) Mbc[r] = (j < nv) ? 0.f : -1e30f;
        const int np128 = (nv + 127) & ~127;
        if (j >= np128) return;
        uint2* kd = reinterpret_cast<uint2*>(Kc + (size_t)r * HID_C + tid * 4);
        uint2* vd = reinterpret_cast<uint2*>(Vc + (size_t)r * HID_C + tid * 4);
        if (j < nv) {
            const int src = cidx[b * S_LEN + j];
            const float4 kv = *reinterpret_cast<const float4*>(
                key + ((size_t)b * S_LEN + src) * HID_C + tid * 4);
            const float4 vv = *reinterpret_cast<const float4*>(
                value + ((size_t)b * S_LEN + src) * HID_C + tid * 4);
            uint2 kp, vp;
            kp.x = ((unsigned)f32_to_bf16_rn(kv.y) << 16) | f32_to_bf16_rn(kv.x);
            kp.y = ((unsigned)f32_to_bf16_rn(kv.w) << 16) | f32_to_bf16_rn(kv.z);
            vp.x = ((unsigned)f32_to_bf16_rn(vv.y) << 16) | f32_to_bf16_rn(vv.x);
            vp.y = ((unsigned)f32_to_bf16_rn(vv.w) << 16) | f32_to_bf16_rn(vv.z);
            *kd = kp; *vd = vp;
        } else {
            *kd = make_uint2(0u, 0u); *vd = make_uint2(0u, 0u);
        }
    }
}

// ---------------------------------------------------------------------------
// shared GEMM core (unchanged from R17)
// ---------------------------------------------------------------------------
__device__ __forceinline__ void gemm_core(
    const ushort_t* __restrict__ Ab, const ushort_t* __restrict__ Wb,
    const float* __restrict__ bias, ushort_t* __restrict__ outB,
    int bm, int bn, int N, int K, float oscale, bool rowBias,
    ushort_t* Ah, ushort_t* Bh)
{
    const int tid  = threadIdx.x;
    const int lane = tid & 63;
    const int wave = tid >> 6;
    const int wm = (wave >> 1) * 64;
    const int wn = (wave & 1) * 64;
    const int fr = lane & 15;
    const int kq = lane >> 4;

    int srow[2], skq[2];
#pragma unroll
    for (int i = 0; i < 2; ++i) {
        const int s = i * 256 + tid;
        srow[i] = s >> 2;
        skq[i] = (s & 3) ^ ((s >> 3) & 3);
    }
    const int wslot = tid & 192;

    f32x4 acc[4][4];
#pragma unroll
    for (int i = 0; i < 4; ++i)
#pragma unroll
        for (int j = 0; j < 4; ++j)
#pragma unroll
            for (int r = 0; r < 4; ++r) acc[i][j][r] = 0.f;

    for (int k0 = 0; k0 < K; k0 += 32) {
        __syncthreads();
#pragma unroll
        for (int i = 0; i < 2; ++i) {
            const int sb = (i * 256 + wslot) * 8;
            gload16(Ab + (size_t)(bm + srow[i]) * K + k0 + skq[i] * 8, Ah + sb);
            gload16(Wb + (size_t)(bn + srow[i]) * K + k0 + skq[i] * 8, Bh + sb);
        }
        __syncthreads();

        bf16x8 fah[4], fbh[4];
#pragma unroll
        for (int mi = 0; mi < 4; ++mi) {
            const int rr = wm + mi * 16 + fr;
            fah[mi] = *reinterpret_cast<const bf16x8*>(
                Ah + (rr * 4 + (kq ^ ((rr >> 1) & 3))) * 8);
        }
#pragma unroll
        for (int ni = 0; ni < 4; ++ni) {
            const int rr = wn + ni * 16 + fr;
            fbh[ni] = *reinterpret_cast<const bf16x8*>(
                Bh + (rr * 4 + (kq ^ ((rr >> 1) & 3))) * 8);
        }

#pragma unroll
        for (int mi = 0; mi < 4; ++mi)
#pragma unroll
            for (int ni = 0; ni < 4; ++ni)
                acc[mi][ni] = __builtin_amdgcn_mfma_f32_16x16x32_bf16(
                    fah[mi], fbh[ni], acc[mi][ni], 0, 0, 0);
    }

    const int fq = lane >> 4;
    if (rowBias) {
#pragma unroll
        for (int mi = 0; mi < 4; ++mi)
#pragma unroll
            for (int r = 0; r < 4; ++r) {
                const int row = bm + wm + mi * 16 + fq * 4 + r;
                const float bvr = bias[row];
#pragma unroll
                for (int ni = 0; ni < 4; ++ni)
                    outB[(size_t)row * N + bn + wn + ni * 16 + fr] =
                        f32_to_bf16_rn((acc[mi][ni][r] + bvr) * oscale);
            }
    } else {
        float bv[4];
#pragma unroll
        for (int ni = 0; ni < 4; ++ni) bv[ni] = bias[bn + wn + ni * 16 + fr];
#pragma unroll
        for (int mi = 0; mi < 4; ++mi)
#pragma unroll
            for (int ni = 0; ni < 4; ++ni) {
                const size_t rowb = (size_t)(bm + wm + mi * 16 + fq * 4);
                const int col = bn + wn + ni * 16 + fr;
#pragma unroll
                for (int r = 0; r < 4; ++r)
                    outB[(rowb + r) * N + col] =
                        f32_to_bf16_rn((acc[mi][ni][r] + bv[ni]) * oscale);
            }
    }
}

// ---------------------------------------------------------------------------
// fused Q/K/V^T projections (unchanged)
// ---------------------------------------------------------------------------
__global__ __launch_bounds__(256) void proj_fused(
    const ushort_t* __restrict__ Qbf, const ushort_t* __restrict__ Kc,
    const ushort_t* __restrict__ Wvb, const ushort_t* __restrict__ Vc,
    const ushort_t* __restrict__ Wqb, const ushort_t* __restrict__ Wkb,
    const float* __restrict__ bq, const float* __restrict__ bk,
    const float* __restrict__ bv, const int* __restrict__ npads,
    ushort_t* __restrict__ Qb, ushort_t* __restrict__ Kb,
    ushort_t* __restrict__ Vtg, float sc2)
{
    __shared__ __align__(16) ushort_t Ah[128 * 32];
    __shared__ __align__(16) ushort_t Bh[128 * 32];

    int id = blockIdx.x;
    if (id < 512) {
        gemm_core(Qbf, Wqb, bq, Qb, (id >> 3) * 128, (id & 7) * 128,
                  HID_C, HID_C, sc2, false, Ah, Bh);
    } else if (id < 1024) {
        id -= 512;
        const int bm = (id >> 3) * 128;
        if ((bm & 2047) >= npads[bm >> 11]) return;
        gemm_core(Kc, Wkb, bk, Kb, bm, (id & 7) * 128,
                  HID_C, HID_C, 1.f, false, Ah, Bh);
    } else {
        id -= 1024;
        const int bn = (id & 63) * 128;
        if ((bn & 2047) >= npads[bn >> 11]) return;
        gemm_core(Wvb, Vc, bv, Vtg, (id >> 6) * 128, bn,
                  4 * S_LEN, HID_C, 1.f, true, Ah, Bh);
    }
}

// ---------------------------------------------------------------------------
// O-GEMM (unchanged)
// ---------------------------------------------------------------------------
__global__ __launch_bounds__(256) void gemm_out(
    const ushort_t* __restrict__ Xhi, const ushort_t* __restrict__ Xlo,
    const ushort_t* __restrict__ Wb, const float* __restrict__ bias,
    float* __restrict__ outF, int M, int N, int K)
{
    __shared__ __align__(16) ushort_t Ah[128 * 32];
    __shared__ __align__(16) ushort_t Al[128 * 32];
    __shared__ __align__(16) ushort_t Bh[128 * 32];

    const int tid  = threadIdx.x;
    const int lane = tid & 63;
    const int wave = tid >> 6;
    const int bm = blockIdx.y * 128;
    const int bn = blockIdx.x * 128;
    const int wm = (wave >> 1) * 64;
    const int wn = (wave & 1) * 64;
    const int fr = lane & 15;
    const int kq = lane >> 4;

    int srow[2], skq[2];
#pragma unroll
    for (int i = 0; i < 2; ++i) {
        const int s = i * 256 + tid;
        srow[i] = s >> 2;
        skq[i] = (s & 3) ^ ((s >> 3) & 3);
    }
    const int wslot = tid & 192;

    f32x4 acc[4][4];
#pragma unroll
    for (int i = 0; i < 4; ++i)
#pragma unroll
        for (int j = 0; j < 4; ++j)
#pragma unroll
            for (int r = 0; r < 4; ++r) acc[i][j][r] = 0.f;

    for (int k0 = 0; k0 < K; k0 += 32) {
        __syncthreads();
#pragma unroll
        for (int i = 0; i < 2; ++i) {
            const int sb = (i * 256 + wslot) * 8;
            const size_t ga = (size_t)(bm + srow[i]) * K + k0 + skq[i] * 8;
            gload16(Xhi + ga, Ah + sb);
            gload16(Xlo + ga, Al + sb);
            gload16(Wb + (size_t)(bn + srow[i]) * K + k0 + skq[i] * 8, Bh + sb);
        }
        __syncthreads();

        bf16x8 fah[4], fal[4], fbh[4];
#pragma unroll
        for (int mi = 0; mi < 4; ++mi) {
            const int rr = wm + mi * 16 + fr;
            const int sl = (rr * 4 + (kq ^ ((rr >> 1) & 3))) * 8;
            fah[mi] = *reinterpret_cast<const bf16x8*>(Ah + sl);
            fal[mi] = *reinterpret_cast<const bf16x8*>(Al + sl);
        }
#pragma unroll
        for (int ni = 0; ni < 4; ++ni) {
            const int rr = wn + ni * 16 + fr;
            fbh[ni] = *reinterpret_cast<const bf16x8*>(
                Bh + (rr * 4 + (kq ^ ((rr >> 1) & 3))) * 8);
        }

#pragma unroll
        for (int mi = 0; mi < 4; ++mi)
#pragma unroll
            for (int ni = 0; ni < 4; ++ni) {
                acc[mi][ni] = __builtin_amdgcn_mfma_f32_16x16x32_bf16(
                    fah[mi], fbh[ni], acc[mi][ni], 0, 0, 0);
                acc[mi][ni] = __builtin_amdgcn_mfma_f32_16x16x32_bf16(
                    fal[mi], fbh[ni], acc[mi][ni], 0, 0, 0);
            }
    }

    const int fq = lane >> 4;
    float bv[4];
#pragma unroll
    for (int ni = 0; ni < 4; ++ni) bv[ni] = bias[bn + wn + ni * 16 + fr];
#pragma unroll
    for (int mi = 0; mi < 4; ++mi)
#pragma unroll
        for (int ni = 0; ni < 4; ++ni) {
            const size_t rowb = (size_t)(bm + wm + mi * 16 + fq * 4);
            const int col = bn + wn + ni * 16 + fr;
#pragma unroll
            for (int r = 0; r < 4; ++r)
                outF[(rowb + r) * N + col] = acc[mi][ni][r] + bv[ni];
        }
}

// ---------------------------------------------------------------------------
// Flash attention (R18): gload_lds-staged K/V, double-buffered, ONE barrier
// per iteration, zero staging registers. LDS linear 512-slot tiles with
// pre-swizzled SOURCE (slot s <- row s>>3, chunk (s&7)^((s>>3)&7)) and the
// same XOR on the read side (slot = row*8 + (c ^ (row&7))) — rule #21.
// Rest as R17: 32x32 swapped QK^T, in-reg P, raw v_exp_f32, compacted keys,
// mask only in final tile, tree reductions, XCD-affinity, defer-max.
// ---------------------------------------------------------------------------
#define QBLK 128
#define KVB  64

__global__ __launch_bounds__(256) void flash_attn_bf16(
    const ushort_t* __restrict__ Qb, const ushort_t* __restrict__ Kb,
    const ushort_t* __restrict__ Vtg, const float* __restrict__ maskb,
    const int* __restrict__ npads,
    ushort_t* __restrict__ Xhi, ushort_t* __restrict__ Xlo)
{
    __shared__ __align__(16) ushort_t Ks[2][512 * 8];   // 8KB per buffer
    __shared__ __align__(16) ushort_t Vt[2][512 * 8];
    __shared__ float Xpose[QBLK];

    const int n  = blockIdx.x;
    const int bh = (n & 7) * 8 + ((n >> 3) & 7);
    const int qx = n >> 6;
    const int b  = bh >> 4;
    const int h  = bh & 15;
    const int q0 = qx * QBLK;

    const int tid  = threadIdx.x;
    const int lane = tid & 63;
    const int w    = tid >> 6;
    const int lq = lane & 31;
    const int lh = lane >> 5;

    const size_t bS = (size_t)b * S_LEN;
    const int hc = h * HDIM;
    const int npad = npads[b];

    bf16x8 qf[4];
#pragma unroll
    for (int s = 0; s < 4; ++s)
        qf[s] = *reinterpret_cast<const bf16x8*>(
            &Qb[(bS + q0 + w * 32 + lq) * HID_C + hc + s * 16 + lh * 8]);

    f32x16 OV[2], zc;
#pragma unroll
    for (int r = 0; r < 16; ++r) { OV[0][r] = 0.f; OV[1][r] = 0.f; zc[r] = 0.f; }
    float m_ = -1e30f, l_ = 0.f;

    // staging slots: s_i = i*256 + tid; row = s>>3; chunk = (s&7)^(row&7)
    const int wslot = tid & 192;
    int srow[2], schk[2];
#pragma unroll
    for (int i = 0; i < 2; ++i) {
        const int s = i * 256 + tid;
        srow[i] = s >> 3;
        schk[i] = (s & 7) ^ ((s >> 3) & 7);
    }
    // per-lane global source bases (t = 0)
    const ushort_t* ksrc[2];
    const ushort_t* vsrc[2];
#pragma unroll
    for (int i = 0; i < 2; ++i) {
        ksrc[i] = Kb + (bS + srow[i]) * HID_C + hc + schk[i] * 8;
        vsrc[i] = Vtg + (size_t)(hc + srow[i]) * (4 * S_LEN) + bS + schk[i] * 8;
    }

    // prologue: stage tile 0 into buffer 0
#pragma unroll
    for (int i = 0; i < 2; ++i) {
        const int sb = (i * 256 + wslot) * 8;
        gload16(ksrc[i], &Ks[0][sb]);
        gload16(vsrc[i], &Vt[0][sb]);
    }
    __syncthreads();   // drains vmcnt(0): tile 0 ready

    // read slot helper: data (row, chunk c) at slot row*8 + (c ^ (row&7))
    for (int t = 0; t < npad; t += KVB) {
        const int  cur  = (t >> 6) & 1;
        const bool more = (t + KVB < npad);

        // ---- issue next-tile gloads into buf[cur^1] (nobody reads it now) ----
        if (more) {
#pragma unroll
            for (int i = 0; i < 2; ++i) {
                const int sb = (i * 256 + wslot) * 8;
                gload16(ksrc[i] + (size_t)(t + KVB) * HID_C, &Ks[cur ^ 1][sb]);
                gload16(vsrc[i] + (t + KVB),                 &Vt[cur ^ 1][sb]);
            }
        }

        // ---- QK^T (swapped, 32x32x16), zero-C first MFMA ----
        f32x16 S[2];
        __builtin_amdgcn_s_setprio(1);
#pragma unroll
        for (int kt = 0; kt < 2; ++kt) {
            const int row = kt * 32 + lq;
            const int rx  = row & 7;
            bf16x8 kf0 = *reinterpret_cast<const bf16x8*>(
                &Ks[cur][(row * 8 + (lh ^ rx)) * 8]);
            S[kt] = __builtin_amdgcn_mfma_f32_32x32x16_bf16(kf0, qf[0], zc, 0, 0, 0);
#pragma unroll
            for (int s = 1; s < 4; ++s) {
                bf16x8 kf = *reinterpret_cast<const bf16x8*>(
                    &Ks[cur][(row * 8 + ((s * 2 + lh) ^ rx)) * 8]);
                S[kt] = __builtin_amdgcn_mfma_f32_32x32x16_bf16(
                    kf, qf[s], S[kt], 0, 0, 0);
            }
        }
        __builtin_amdgcn_s_setprio(0);

        // ---- mask bias: only the FINAL tile can contain padded keys ----
        if (!more) {
#pragma unroll
            for (int kt = 0; kt < 2; ++kt)
#pragma unroll
                for (int g = 0; g < 4; ++g) {
                    float4 mv = *reinterpret_cast<const float4*>(
                        &maskb[bS + t + kt * 32 + g * 8 + lh * 4]);
#pragma unroll
                    for (int e = 0; e < 4; ++e)
                        S[kt][g * 4 + e] += reinterpret_cast<const float*>(&mv)[e];
                }
        }

        // ---- tree row-max (one q per lane) ----
        float mx = fmaxf(tmax16(S[0]), tmax16(S[1]));
        mx = fmaxf(mx, __shfl_xor(mx, 32));

        // ---- defer-max (rare rescale) ----
        if (!__all(mx <= m_ + 8.f)) {
            float mn = fmaxf(m_, mx);
            float corr = fexp2(m_ - mn);
            m_ = mn; l_ *= corr;
            if (lh == 0) Xpose[w * 32 + lq] = corr;   // same-wave RAW
#pragma unroll
            for (int r = 0; r < 16; ++r) {
                float cq = Xpose[w * 32 + (r & 3) + 8 * (r >> 2) + 4 * lh];
                OV[0][r] *= cq;
                OV[1][r] *= cq;
            }
        }

        // ---- P = exp2(S - m) via raw v_exp_f32, tree row-sum ----
#pragma unroll
        for (int kt = 0; kt < 2; ++kt)
#pragma unroll
            for (int r = 0; r < 16; ++r) S[kt][r] = fexp2(S[kt][r] - m_);
        float ls = tsum16(S[0]) + tsum16(S[1]);
        ls += __shfl_xor(ls, 32);
        l_ += ls;

        // ---- P -> PV A-frags in registers (cvt_pk + permlane32_swap) ----
        bf16x8 pa[4];
#pragma unroll
        for (int kt = 0; kt < 2; ++kt)
#pragma unroll
            for (int u = 0; u < 2; ++u) {
                const int bb = u * 8;
                unsigned int c0, c1, c2, c3;
                asm("v_cvt_pk_bf16_f32 %0, %1, %2"
                    : "=v"(c0) : "v"(S[kt][bb + 0]), "v"(S[kt][bb + 1]));
                asm("v_cvt_pk_bf16_f32 %0, %1, %2"
                    : "=v"(c1) : "v"(S[kt][bb + 2]), "v"(S[kt][bb + 3]));
                asm("v_cvt_pk_bf16_f32 %0, %1, %2"
                    : "=v"(c2) : "v"(S[kt][bb + 4]), "v"(S[kt][bb + 5]));
                asm("v_cvt_pk_bf16_f32 %0, %1, %2"
                    : "=v"(c3) : "v"(S[kt][bb + 6]), "v"(S[kt][bb + 7]));
                asm("v_permlane32_swap_b32 %0, %1" : "+v"(c0), "+v"(c2));
                asm("v_permlane32_swap_b32 %0, %1" : "+v"(c1), "+v"(c3));
                uint4 wv = make_uint4(c0, c1, c2, c3);
                pa[kt * 2 + u] = *reinterpret_cast<bf16x8*>(&wv);
            }

        // ---- PV (32x32x16) from buf[cur] ----
        __builtin_amdgcn_s_setprio(1);
#pragma unroll
        for (int dt = 0; dt < 2; ++dt) {
            const int row = dt * 32 + lq;
            const int rx  = row & 7;
#pragma unroll
            for (int f = 0; f < 4; ++f) {
                bf16x8 vf = *reinterpret_cast<const bf16x8*>(
                    &Vt[cur][(row * 8 + ((f * 2 + lh) ^ rx)) * 8]);
                OV[dt] = __builtin_amdgcn_mfma_f32_32x32x16_bf16(
                    pa[f], vf, OV[dt], 0, 0, 0);
            }
        }
        __builtin_amdgcn_s_setprio(0);

        // ---- single barrier: drains vmcnt (next tile ready) + ends reads ----
        __syncthreads();
    }

    // ---- epilogue: x = OV/l, pre-split hi/lo bf16 ----
    if (lh == 0) Xpose[w * 32 + lq] = 1.f / l_;   // same-wave RAW
#pragma unroll
    for (int r = 0; r < 16; ++r) {
        const int qr = (r & 3) + 8 * (r >> 2) + 4 * lh;
        const float inv = Xpose[w * 32 + qr];
        const size_t row = bS + q0 + w * 32 + qr;
#pragma unroll
        for (int dt = 0; dt < 2; ++dt) {
            float v = OV[dt][r] * inv;
            unsigned int u = __float_as_uint(v);
            unsigned short hi = (unsigned short)(u >> 16);
            float res = v - __uint_as_float(u & 0xFFFF0000u);
            Xhi[row * HID_C + hc + dt * 32 + lq] = hi;
            Xlo[row * HID_C + hc + dt * 32 + lq] = f32_to_bf16_rn(res);
        }
    }
}

// ---------------------------------------------------------------------------
extern "C" void kernel_launch(void* const* d_in, const int* in_sizes, int n_in,
                              void* d_out, int out_size, void* d_ws, size_t ws_size,
                              hipStream_t stream) {
    const float* query = (const float*)d_in[0];
    const float* key   = (const float*)d_in[1];
    const float* value = (const float*)d_in[2];
    const int*   mask  = (const int*)d_in[3];
    const float* Wq = (const float*)d_in[4];
    const float* bq = (const float*)d_in[5];
    const float* Wk = (const float*)d_in[6];
    const float* bk = (const float*)d_in[7];
    const float* Wv = (const float*)d_in[8];
    const float* bv = (const float*)d_in[9];
    const float* Wo = (const float*)d_in[10];
    const float* bo = (const float*)d_in[11];
    float* out = (float*)d_out;

    const int B = 4, M = B * S_LEN;          // 8192
    const size_t seg = (size_t)M * HID_C;
    const size_t nw  = (size_t)HID_C * HID_C;

    ushort_t* Qb  = (ushort_t*)d_ws;         // 16MB each
    ushort_t* Kb  = Qb + seg;
    ushort_t* Vtg = Kb + seg;                // V^T: [1024 feat][8192 compact tok]
    ushort_t* Xhi = Vtg + seg;               // aliased: Kc before attn
    ushort_t* Xlo = Xhi + seg;               // aliased: Vc before attn
    ushort_t* Qbf = Xlo + seg;               // query bf16
    float*    Mbc = (float*)(Qbf + seg);     // 32KB compact mask bias
    ushort_t* Wqb = (ushort_t*)(Mbc + 4 * S_LEN);
    ushort_t* Wkb = Wqb + nw;                // 2MB each
    ushort_t* Wob = Wkb + nw;
    ushort_t* Wvb = Wob + nw;
    int*      cidx   = (int*)(Wvb + nw);     // 32KB
    int*      nvalid = cidx + 4 * S_LEN;
    int*      npads  = nvalid + 4;           // total ~105MB

    ushort_t* Kc = Xhi;                      // compact bf16 key rows
    ushort_t* Vc = Xlo;                      // compact bf16 value rows

    scan_mask<<<dim3(4), 64, 0, stream>>>(mask, cidx, nvalid, npads);
    prep_gather<<<dim3(CONVB + M), 256, 0, stream>>>(
        query, Wq, Wk, Wo, Wv, key, value, cidx, nvalid,
        Qbf, Wqb, Wkb, Wob, Wvb, Kc, Vc, Mbc);

    const float SC2 = 0.125f * LOG2E;
    proj_fused<<<dim3(1536), 256, 0, stream>>>(
        Qbf, Kc, Wvb, Vc, Wqb, Wkb, bq, bk, bv, npads, Qb, Kb, Vtg, SC2);

    flash_attn_bf16<<<dim3((S_LEN / QBLK) * B * NHEADS), 256, 0, stream>>>(
        Qb, Kb, Vtg, Mbc, npads, Xhi, Xlo);

    gemm_out<<<dim3(HID_C / 128, M / 128), 256, 0, stream>>>(
        Xhi, Xlo, Wob, bo, out, M, HID_C, HID_C);
}

// Round 19
// 199.358 us; speedup vs baseline: 1.0360x; 1.0360x over previous
//
#include <hip/hip_runtime.h>
#include <cstddef>
#include <math.h>

#define S_LEN  2048
#define HID_C  1024
#define NHEADS 16
#define HDIM   64

typedef __attribute__((ext_vector_type(8))) short bf16x8;
typedef __attribute__((ext_vector_type(4))) float f32x4;
typedef __attribute__((ext_vector_type(16))) float f32x16;
typedef unsigned short ushort_t;

#define LOG2E 1.44269504088896f

__device__ __forceinline__ unsigned short f32_to_bf16_rn(float f) {
    unsigned int u = __float_as_uint(f);
    return (unsigned short)((u + 0x8000u) >> 16);
}

// raw hardware exp2: one v_exp_f32 (vs exp2f's multi-instruction ocml call)
__device__ __forceinline__ float fexp2(float x) {
    float r;
    asm("v_exp_f32 %0, %1" : "=v"(r) : "v"(x));
    return r;
}

// direct global->LDS 16B copy (lds dest = wave-uniform base + lane*16)
__device__ __forceinline__ void gload16(const ushort_t* g, ushort_t* l) {
    __builtin_amdgcn_global_load_lds(
        (const __attribute__((address_space(1))) void*)g,
        (__attribute__((address_space(3))) void*)l, 16, 0, 0);
}

// balanced tree reductions over f32x16 (depth 5; max3-fusable)
__device__ __forceinline__ float tmax16(const f32x16& v) {
    float a0 = fmaxf(v[0], v[1]),   a1 = fmaxf(v[2], v[3]);
    float a2 = fmaxf(v[4], v[5]),   a3 = fmaxf(v[6], v[7]);
    float a4 = fmaxf(v[8], v[9]),   a5 = fmaxf(v[10], v[11]);
    float a6 = fmaxf(v[12], v[13]), a7 = fmaxf(v[14], v[15]);
    float b0 = fmaxf(a0, a1), b1 = fmaxf(a2, a3);
    float b2 = fmaxf(a4, a5), b3 = fmaxf(a6, a7);
    return fmaxf(fmaxf(b0, b1), fmaxf(b2, b3));
}
__device__ __forceinline__ float tsum16(const f32x16& v) {
    float a0 = v[0] + v[1],   a1 = v[2] + v[3];
    float a2 = v[4] + v[5],   a3 = v[6] + v[7];
    float a4 = v[8] + v[9],   a5 = v[10] + v[11];
    float a6 = v[12] + v[13], a7 = v[14] + v[15];
    float b0 = a0 + a1, b1 = a2 + a3, b2 = a4 + a5, b3 = a6 + a7;
    return (b0 + b1) + (b2 + b3);
}

// ---------------------------------------------------------------------------
// scan: order-preserving compaction of valid key indices per batch.
// ---------------------------------------------------------------------------
__global__ void scan_mask(const int* __restrict__ mask, int* __restrict__ cidx,
                          int* __restrict__ nvalid, int* __restrict__ npads) {
    const int b = blockIdx.x;
    const int lane = threadIdx.x;           // blockDim.x == 64
    int base = 0;
    for (int i = 0; i < S_LEN / 64; ++i) {
        const int s = i * 64 + lane;
        const int v = mask[b * S_LEN + s];
        const unsigned long long bal = __ballot(v != 0);
        const int pre = __popcll(bal & ((1ull << lane) - 1ull));
        if (v) cidx[b * S_LEN + base + pre] = s;
        base += (int)__popcll(bal);
    }
    if (lane == 0) { nvalid[b] = base; npads[b] = (base + 63) & ~63; }
}

// ---------------------------------------------------------------------------
// fused prep + gather (unchanged)
// ---------------------------------------------------------------------------
#define CONVB 12288

__global__ void prep_gather(
    const float* __restrict__ query,
    const float* __restrict__ Wq, const float* __restrict__ Wk,
    const float* __restrict__ Wo, const float* __restrict__ Wv,
    const float* __restrict__ key, const float* __restrict__ value,
    const int* __restrict__ cidx, const int* __restrict__ nvalid,
    ushort_t* __restrict__ Qbf, ushort_t* __restrict__ Wqb,
    ushort_t* __restrict__ Wkb, ushort_t* __restrict__ Wob,
    ushort_t* __restrict__ Wvb,
    ushort_t* __restrict__ Kc, ushort_t* __restrict__ Vc,
    float* __restrict__ Mbc)
{
    if (blockIdx.x < CONVB) {
        const unsigned SEG = 4u * S_LEN * HID_C;
        const unsigned NW = HID_C * HID_C;
        unsigned i = (blockIdx.x * 256u + threadIdx.x) * 4u;
        const float* src; ushort_t* dst;
        if (i < SEG) { src = query; dst = Qbf; }
        else {
            i -= SEG;
            if (i < NW) { src = Wq; dst = Wqb; }
            else { i -= NW;
                if (i < NW) { src = Wk; dst = Wkb; }
                else { i -= NW;
                    if (i < NW) { src = Wo; dst = Wob; }
                    else { i -= NW; if (i >= NW) return; src = Wv; dst = Wvb; }
                }
            }
        }
        float4 v = *reinterpret_cast<const float4*>(src + i);
        uint2 p;
        p.x = ((unsigned)f32_to_bf16_rn(v.y) << 16) | f32_to_bf16_rn(v.x);
        p.y = ((unsigned)f32_to_bf16_rn(v.w) << 16) | f32_to_bf16_rn(v.z);
        *reinterpret_cast<uint2*>(dst + i) = p;
    } else {
        const int r = blockIdx.x - CONVB;       // 0..8191 compact row
        const int b = r >> 11, j = r & 2047;
        const int tid = threadIdx.x;
        const int nv = nvalid[b];
        if (tid == 0) Mbc[r] = (j < nv) ? 0.f : -1e30f;
        const int np128 = (nv + 127) & ~127;
        if (j >= np128) return;
        uint2* kd = reinterpret_cast<uint2*>(Kc + (size_t)r * HID_C + tid * 4);
        uint2* vd = reinterpret_cast<uint2*>(Vc + (size_t)r * HID_C + tid * 4);
        if (j < nv) {
            const int src = cidx[b * S_LEN + j];
            const float4 kv = *reinterpret_cast<const float4*>(
                key + ((size_t)b * S_LEN + src) * HID_C + tid * 4);
            const float4 vv = *reinterpret_cast<const float4*>(
                value + ((size_t)b * S_LEN + src) * HID_C + tid * 4);
            uint2 kp, vp;
            kp.x = ((unsigned)f32_to_bf16_rn(kv.y) << 16) | f32_to_bf16_rn(kv.x);
            kp.y = ((unsigned)f32_to_bf16_rn(kv.w) << 16) | f32_to_bf16_rn(kv.z);
            vp.x = ((unsigned)f32_to_bf16_rn(vv.y) << 16) | f32_to_bf16_rn(vv.x);
            vp.y = ((unsigned)f32_to_bf16_rn(vv.w) << 16) | f32_to_bf16_rn(vv.z);
            *kd = kp; *vd = vp;
        } else {
            *kd = make_uint2(0u, 0u); *vd = make_uint2(0u, 0u);
        }
    }
}

// ---------------------------------------------------------------------------
// shared GEMM core, BK=64 (R19): halves barrier/drain rendezvous vs BK=32.
// LDS linear [1024 slots x 16B]; slot s holds (row=s>>3, chunk=(s&7)^((s>>3)&7));
// fragment read slot = row*8 + (c ^ (row&7)), c = half*4 + kq -> 2-way banks.
// ---------------------------------------------------------------------------
__device__ __forceinline__ void gemm_core(
    const ushort_t* __restrict__ Ab, const ushort_t* __restrict__ Wb,
    const float* __restrict__ bias, ushort_t* __restrict__ outB,
    int bm, int bn, int N, int K, float oscale, bool rowBias,
    ushort_t* Ah, ushort_t* Bh)
{
    const int tid  = threadIdx.x;
    const int lane = tid & 63;
    const int wave = tid >> 6;
    const int wm = (wave >> 1) * 64;
    const int wn = (wave & 1) * 64;
    const int fr = lane & 15;
    const int kq = lane >> 4;

    int srow[4], schk[4];
#pragma unroll
    for (int i = 0; i < 4; ++i) {
        const int s = i * 256 + tid;
        srow[i] = s >> 3;
        schk[i] = (s & 7) ^ ((s >> 3) & 7);
    }
    const int wslot = tid & 192;

    f32x4 acc[4][4];
#pragma unroll
    for (int i = 0; i < 4; ++i)
#pragma unroll
        for (int j = 0; j < 4; ++j)
#pragma unroll
            for (int r = 0; r < 4; ++r) acc[i][j][r] = 0.f;

    for (int k0 = 0; k0 < K; k0 += 64) {
        __syncthreads();
#pragma unroll
        for (int i = 0; i < 4; ++i) {
            const int sb = (i * 256 + wslot) * 8;
            gload16(Ab + (size_t)(bm + srow[i]) * K + k0 + schk[i] * 8, Ah + sb);
            gload16(Wb + (size_t)(bn + srow[i]) * K + k0 + schk[i] * 8, Bh + sb);
        }
        __syncthreads();

#pragma unroll
        for (int h = 0; h < 2; ++h) {
            bf16x8 fah[4], fbh[4];
            const int c = h * 4 + kq;
#pragma unroll
            for (int mi = 0; mi < 4; ++mi) {
                const int rr = wm + mi * 16 + fr;
                fah[mi] = *reinterpret_cast<const bf16x8*>(
                    Ah + (rr * 8 + (c ^ (rr & 7))) * 8);
            }
#pragma unroll
            for (int ni = 0; ni < 4; ++ni) {
                const int rr = wn + ni * 16 + fr;
                fbh[ni] = *reinterpret_cast<const bf16x8*>(
                    Bh + (rr * 8 + (c ^ (rr & 7))) * 8);
            }
#pragma unroll
            for (int mi = 0; mi < 4; ++mi)
#pragma unroll
                for (int ni = 0; ni < 4; ++ni)
                    acc[mi][ni] = __builtin_amdgcn_mfma_f32_16x16x32_bf16(
                        fah[mi], fbh[ni], acc[mi][ni], 0, 0, 0);
        }
    }

    const int fq = lane >> 4;
    if (rowBias) {
#pragma unroll
        for (int mi = 0; mi < 4; ++mi)
#pragma unroll
            for (int r = 0; r < 4; ++r) {
                const int row = bm + wm + mi * 16 + fq * 4 + r;
                const float bvr = bias[row];
#pragma unroll
                for (int ni = 0; ni < 4; ++ni)
                    outB[(size_t)row * N + bn + wn + ni * 16 + fr] =
                        f32_to_bf16_rn((acc[mi][ni][r] + bvr) * oscale);
            }
    } else {
        float bv[4];
#pragma unroll
        for (int ni = 0; ni < 4; ++ni) bv[ni] = bias[bn + wn + ni * 16 + fr];
#pragma unroll
        for (int mi = 0; mi < 4; ++mi)
#pragma unroll
            for (int ni = 0; ni < 4; ++ni) {
                const size_t rowb = (size_t)(bm + wm + mi * 16 + fq * 4);
                const int col = bn + wn + ni * 16 + fr;
#pragma unroll
                for (int r = 0; r < 4; ++r)
                    outB[(rowb + r) * N + col] =
                        f32_to_bf16_rn((acc[mi][ni][r] + bv[ni]) * oscale);
            }
    }
}

// ---------------------------------------------------------------------------
// fused Q/K/V^T projections (BK=64 core)
// ---------------------------------------------------------------------------
__global__ __launch_bounds__(256) void proj_fused(
    const ushort_t* __restrict__ Qbf, const ushort_t* __restrict__ Kc,
    const ushort_t* __restrict__ Wvb, const ushort_t* __restrict__ Vc,
    const ushort_t* __restrict__ Wqb, const ushort_t* __restrict__ Wkb,
    const float* __restrict__ bq, const float* __restrict__ bk,
    const float* __restrict__ bv, const int* __restrict__ npads,
    ushort_t* __restrict__ Qb, ushort_t* __restrict__ Kb,
    ushort_t* __restrict__ Vtg, float sc2)
{
    __shared__ __align__(16) ushort_t Ah[128 * 64];
    __shared__ __align__(16) ushort_t Bh[128 * 64];

    int id = blockIdx.x;
    if (id < 512) {
        gemm_core(Qbf, Wqb, bq, Qb, (id >> 3) * 128, (id & 7) * 128,
                  HID_C, HID_C, sc2, false, Ah, Bh);
    } else if (id < 1024) {
        id -= 512;
        const int bm = (id >> 3) * 128;
        if ((bm & 2047) >= npads[bm >> 11]) return;
        gemm_core(Kc, Wkb, bk, Kb, bm, (id & 7) * 128,
                  HID_C, HID_C, 1.f, false, Ah, Bh);
    } else {
        id -= 1024;
        const int bn = (id & 63) * 128;
        if ((bn & 2047) >= npads[bn >> 11]) return;
        gemm_core(Wvb, Vc, bv, Vtg, (id >> 6) * 128, bn,
                  4 * S_LEN, HID_C, 1.f, true, Ah, Bh);
    }
}

// ---------------------------------------------------------------------------
// O-GEMM: fp32 out, split-A (hi/lo, 2 MFMA), BK=64 gload_lds staging.
// ---------------------------------------------------------------------------
__global__ __launch_bounds__(256) void gemm_out(
    const ushort_t* __restrict__ Xhi, const ushort_t* __restrict__ Xlo,
    const ushort_t* __restrict__ Wb, const float* __restrict__ bias,
    float* __restrict__ outF, int M, int N, int K)
{
    __shared__ __align__(16) ushort_t Ah[128 * 64];
    __shared__ __align__(16) ushort_t Al[128 * 64];
    __shared__ __align__(16) ushort_t Bh[128 * 64];

    const int tid  = threadIdx.x;
    const int lane = tid & 63;
    const int wave = tid >> 6;
    const int bm = blockIdx.y * 128;
    const int bn = blockIdx.x * 128;
    const int wm = (wave >> 1) * 64;
    const int wn = (wave & 1) * 64;
    const int fr = lane & 15;
    const int kq = lane >> 4;

    int srow[4], schk[4];
#pragma unroll
    for (int i = 0; i < 4; ++i) {
        const int s = i * 256 + tid;
        srow[i] = s >> 3;
        schk[i] = (s & 7) ^ ((s >> 3) & 7);
    }
    const int wslot = tid & 192;

    f32x4 acc[4][4];
#pragma unroll
    for (int i = 0; i < 4; ++i)
#pragma unroll
        for (int j = 0; j < 4; ++j)
#pragma unroll
            for (int r = 0; r < 4; ++r) acc[i][j][r] = 0.f;

    for (int k0 = 0; k0 < K; k0 += 64) {
        __syncthreads();
#pragma unroll
        for (int i = 0; i < 4; ++i) {
            const int sb = (i * 256 + wslot) * 8;
            const size_t ga = (size_t)(bm + srow[i]) * K + k0 + schk[i] * 8;
            gload16(Xhi + ga, Ah + sb);
            gload16(Xlo + ga, Al + sb);
            gload16(Wb + (size_t)(bn + srow[i]) * K + k0 + schk[i] * 8, Bh + sb);
        }
        __syncthreads();

#pragma unroll
        for (int h = 0; h < 2; ++h) {
            bf16x8 fah[4], fal[4], fbh[4];
            const int c = h * 4 + kq;
#pragma unroll
            for (int mi = 0; mi < 4; ++mi) {
                const int rr = wm + mi * 16 + fr;
                const int sl = (rr * 8 + (c ^ (rr & 7))) * 8;
                fah[mi] = *reinterpret_cast<const bf16x8*>(Ah + sl);
                fal[mi] = *reinterpret_cast<const bf16x8*>(Al + sl);
            }
#pragma unroll
            for (int ni = 0; ni < 4; ++ni) {
                const int rr = wn + ni * 16 + fr;
                fbh[ni] = *reinterpret_cast<const bf16x8*>(
                    Bh + (rr * 8 + (c ^ (rr & 7))) * 8);
            }
#pragma unroll
            for (int mi = 0; mi < 4; ++mi)
#pragma unroll
                for (int ni = 0; ni < 4; ++ni) {
                    acc[mi][ni] = __builtin_amdgcn_mfma_f32_16x16x32_bf16(
                        fah[mi], fbh[ni], acc[mi][ni], 0, 0, 0);
                    acc[mi][ni] = __builtin_amdgcn_mfma_f32_16x16x32_bf16(
                        fal[mi], fbh[ni], acc[mi][ni], 0, 0, 0);
                }
        }
    }

    const int fq = lane >> 4;
    float bv[4];
#pragma unroll
    for (int ni = 0; ni < 4; ++ni) bv[ni] = bias[bn + wn + ni * 16 + fr];
#pragma unroll
    for (int mi = 0; mi < 4; ++mi)
#pragma unroll
        for (int ni = 0; ni < 4; ++ni) {
            const size_t rowb = (size_t)(bm + wm + mi * 16 + fq * 4);
            const int col = bn + wn + ni * 16 + fr;
#pragma unroll
            for (int r = 0; r < 4; ++r)
                outF[(rowb + r) * N + col] = acc[mi][ni][r] + bv[ni];
        }
}

// ---------------------------------------------------------------------------
// Flash attention — EXACTLY the measured-best R17 kernel (80µs): ds_write
// staging, 2 barriers/iter, 32x32 swapped QK^T, in-reg P (cvt_pk+permlane),
// raw v_exp_f32, compacted keys, mask only in final tile, tree reductions,
// XCD-affinity, defer-max, zero-C first MFMA, T14 reg-prefetch.
// ---------------------------------------------------------------------------
#define QBLK 128
#define KVB  64
#define LDA  72

__global__ __launch_bounds__(256) void flash_attn_bf16(
    const ushort_t* __restrict__ Qb, const ushort_t* __restrict__ Kb,
    const ushort_t* __restrict__ Vtg, const float* __restrict__ maskb,
    const int* __restrict__ npads,
    ushort_t* __restrict__ Xhi, ushort_t* __restrict__ Xlo)
{
    __shared__ __align__(16) ushort_t Ks[KVB * LDA];
    __shared__ __align__(16) ushort_t Vt[HDIM * LDA];
    __shared__ float Xpose[QBLK];

    const int n  = blockIdx.x;
    const int bh = (n & 7) * 8 + ((n >> 3) & 7);
    const int qx = n >> 6;
    const int b  = bh >> 4;
    const int h  = bh & 15;
    const int q0 = qx * QBLK;

    const int tid  = threadIdx.x;
    const int lane = tid & 63;
    const int w    = tid >> 6;
    const int lq = lane & 31;
    const int lh = lane >> 5;

    const size_t bS = (size_t)b * S_LEN;
    const int hc = h * HDIM;
    const int npad = npads[b];

    bf16x8 qf[4];
#pragma unroll
    for (int s = 0; s < 4; ++s)
        qf[s] = *reinterpret_cast<const bf16x8*>(
            &Qb[(bS + q0 + w * 32 + lq) * HID_C + hc + s * 16 + lh * 8]);

    f32x16 OV[2], zc;
#pragma unroll
    for (int r = 0; r < 16; ++r) { OV[0][r] = 0.f; OV[1][r] = 0.f; zc[r] = 0.f; }
    float m_ = -1e30f, l_ = 0.f;

    const int sr  = tid >> 2;
    const int seg = tid & 3;
    const ushort_t* kbase = &Kb[(bS + sr) * HID_C + hc + seg * 16];
    const ushort_t* vbase = &Vtg[(size_t)(hc + sr) * (4 * S_LEN) + bS + seg * 16];

    {
        bf16x8 kv0 = *reinterpret_cast<const bf16x8*>(kbase);
        bf16x8 kv1 = *reinterpret_cast<const bf16x8*>(kbase + 8);
        bf16x8 vv0 = *reinterpret_cast<const bf16x8*>(vbase);
        bf16x8 vv1 = *reinterpret_cast<const bf16x8*>(vbase + 8);
        *reinterpret_cast<bf16x8*>(&Ks[sr * LDA + seg * 16])     = kv0;
        *reinterpret_cast<bf16x8*>(&Ks[sr * LDA + seg * 16 + 8]) = kv1;
        *reinterpret_cast<bf16x8*>(&Vt[sr * LDA + seg * 16])     = vv0;
        *reinterpret_cast<bf16x8*>(&Vt[sr * LDA + seg * 16 + 8]) = vv1;
        __syncthreads();
    }

    for (int t = 0; t < npad; t += KVB) {
        // ---- QK^T (swapped, 32x32x16), zero-C first MFMA ----
        f32x16 S[2];
        __builtin_amdgcn_s_setprio(1);
#pragma unroll
        for (int kt = 0; kt < 2; ++kt) {
            bf16x8 kf0 = *reinterpret_cast<const bf16x8*>(
                &Ks[(kt * 32 + lq) * LDA + lh * 8]);
            S[kt] = __builtin_amdgcn_mfma_f32_32x32x16_bf16(kf0, qf[0], zc, 0, 0, 0);
#pragma unroll
            for (int s = 1; s < 4; ++s) {
                bf16x8 kf = *reinterpret_cast<const bf16x8*>(
                    &Ks[(kt * 32 + lq) * LDA + s * 16 + lh * 8]);
                S[kt] = __builtin_amdgcn_mfma_f32_32x32x16_bf16(
                    kf, qf[s], S[kt], 0, 0, 0);
            }
        }
        __builtin_amdgcn_s_setprio(0);

        // ---- T14: issue next-tile K/V loads ----
        const bool more = (t + KVB < npad);
        bf16x8 kv0n, kv1n, vv0n, vv1n;
        if (more) {
            const ushort_t* kp = kbase + (size_t)(t + KVB) * HID_C;
            const ushort_t* vp = vbase + (t + KVB);
            kv0n = *reinterpret_cast<const bf16x8*>(kp);
            kv1n = *reinterpret_cast<const bf16x8*>(kp + 8);
            vv0n = *reinterpret_cast<const bf16x8*>(vp);
            vv1n = *reinterpret_cast<const bf16x8*>(vp + 8);
        }

        // ---- mask bias: only the FINAL tile can contain padded keys ----
        if (!more) {
#pragma unroll
            for (int kt = 0; kt < 2; ++kt)
#pragma unroll
                for (int g = 0; g < 4; ++g) {
                    float4 mv = *reinterpret_cast<const float4*>(
                        &maskb[bS + t + kt * 32 + g * 8 + lh * 4]);
#pragma unroll
                    for (int e = 0; e < 4; ++e)
                        S[kt][g * 4 + e] += reinterpret_cast<const float*>(&mv)[e];
                }
        }

        // ---- tree row-max (one q per lane) ----
        float mx = fmaxf(tmax16(S[0]), tmax16(S[1]));
        mx = fmaxf(mx, __shfl_xor(mx, 32));

        // ---- defer-max (rare rescale) ----
        if (!__all(mx <= m_ + 8.f)) {
            float mn = fmaxf(m_, mx);
            float corr = fexp2(m_ - mn);
            m_ = mn; l_ *= corr;
            if (lh == 0) Xpose[w * 32 + lq] = corr;   // same-wave RAW
#pragma unroll
            for (int r = 0; r < 16; ++r) {
                float cq = Xpose[w * 32 + (r & 3) + 8 * (r >> 2) + 4 * lh];
                OV[0][r] *= cq;
                OV[1][r] *= cq;
            }
        }

        // ---- P = exp2(S - m) via raw v_exp_f32, tree row-sum ----
#pragma unroll
        for (int kt = 0; kt < 2; ++kt)
#pragma unroll
            for (int r = 0; r < 16; ++r) S[kt][r] = fexp2(S[kt][r] - m_);
        float ls = tsum16(S[0]) + tsum16(S[1]);
        ls += __shfl_xor(ls, 32);
        l_ += ls;

        // ---- P -> PV A-frags in registers (cvt_pk + permlane32_swap) ----
        bf16x8 pa[4];
#pragma unroll
        for (int kt = 0; kt < 2; ++kt)
#pragma unroll
            for (int u = 0; u < 2; ++u) {
                const int bb = u * 8;
                unsigned int c0, c1, c2, c3;
                asm("v_cvt_pk_bf16_f32 %0, %1, %2"
                    : "=v"(c0) : "v"(S[kt][bb + 0]), "v"(S[kt][bb + 1]));
                asm("v_cvt_pk_bf16_f32 %0, %1, %2"
                    : "=v"(c1) : "v"(S[kt][bb + 2]), "v"(S[kt][bb + 3]));
                asm("v_cvt_pk_bf16_f32 %0, %1, %2"
                    : "=v"(c2) : "v"(S[kt][bb + 4]), "v"(S[kt][bb + 5]));
                asm("v_cvt_pk_bf16_f32 %0, %1, %2"
                    : "=v"(c3) : "v"(S[kt][bb + 6]), "v"(S[kt][bb + 7]));
                asm("v_permlane32_swap_b32 %0, %1" : "+v"(c0), "+v"(c2));
                asm("v_permlane32_swap_b32 %0, %1" : "+v"(c1), "+v"(c3));
                uint4 wv = make_uint4(c0, c1, c2, c3);
                pa[kt * 2 + u] = *reinterpret_cast<bf16x8*>(&wv);
            }

        // ---- PV (32x32x16) ----
        __builtin_amdgcn_s_setprio(1);
#pragma unroll
        for (int dt = 0; dt < 2; ++dt)
#pragma unroll
            for (int f = 0; f < 4; ++f) {
                bf16x8 vf = *reinterpret_cast<const bf16x8*>(
                    &Vt[(dt * 32 + lq) * LDA + f * 16 + lh * 8]);
                OV[dt] = __builtin_amdgcn_mfma_f32_32x32x16_bf16(
                    pa[f], vf, OV[dt], 0, 0, 0);
            }
        __builtin_amdgcn_s_setprio(0);

        // ---- stage next tile ----
        __syncthreads();
        if (more) {
            *reinterpret_cast<bf16x8*>(&Ks[sr * LDA + seg * 16])     = kv0n;
            *reinterpret_cast<bf16x8*>(&Ks[sr * LDA + seg * 16 + 8]) = kv1n;
            *reinterpret_cast<bf16x8*>(&Vt[sr * LDA + seg * 16])     = vv0n;
            *reinterpret_cast<bf16x8*>(&Vt[sr * LDA + seg * 16 + 8]) = vv1n;
            __syncthreads();
        }
    }

    // ---- epilogue: x = OV/l, pre-split hi/lo bf16 ----
    if (lh == 0) Xpose[w * 32 + lq] = 1.f / l_;   // same-wave RAW
#pragma unroll
    for (int r = 0; r < 16; ++r) {
        const int qr = (r & 3) + 8 * (r >> 2) + 4 * lh;
        const float inv = Xpose[w * 32 + qr];
        const size_t row = bS + q0 + w * 32 + qr;
#pragma unroll
        for (int dt = 0; dt < 2; ++dt) {
            float v = OV[dt][r] * inv;
            unsigned int u = __float_as_uint(v);
            unsigned short hi = (unsigned short)(u >> 16);
            float res = v - __uint_as_float(u & 0xFFFF0000u);
            Xhi[row * HID_C + hc + dt * 32 + lq] = hi;
            Xlo[row * HID_C + hc + dt * 32 + lq] = f32_to_bf16_rn(res);
        }
    }
}

// ---------------------------------------------------------------------------
extern "C" void kernel_launch(void* const* d_in, const int* in_sizes, int n_in,
                              void* d_out, int out_size, void* d_ws, size_t ws_size,
                              hipStream_t stream) {
    const float* query = (const float*)d_in[0];
    const float* key   = (const float*)d_in[1];
    const float* value = (const float*)d_in[2];
    const int*   mask  = (const int*)d_in[3];
    const float* Wq = (const float*)d_in[4];
    const float* bq = (const float*)d_in[5];
    const float* Wk = (const float*)d_in[6];
    const float* bk = (const float*)d_in[7];
    const float* Wv = (const float*)d_in[8];
    const float* bv = (const float*)d_in[9];
    const float* Wo = (const float*)d_in[10];
    const float* bo = (const float*)d_in[11];
    float* out = (float*)d_out;

    const int B = 4, M = B * S_LEN;          // 8192
    const size_t seg = (size_t)M * HID_C;
    const size_t nw  = (size_t)HID_C * HID_C;

    ushort_t* Qb  = (ushort_t*)d_ws;         // 16MB each
    ushort_t* Kb  = Qb + seg;
    ushort_t* Vtg = Kb + seg;                // V^T: [1024 feat][8192 compact tok]
    ushort_t* Xhi = Vtg + seg;               // aliased: Kc before attn
    ushort_t* Xlo = Xhi + seg;               // aliased: Vc before attn
    ushort_t* Qbf = Xlo + seg;               // query bf16
    float*    Mbc = (float*)(Qbf + seg);     // 32KB compact mask bias
    ushort_t* Wqb = (ushort_t*)(Mbc + 4 * S_LEN);
    ushort_t* Wkb = Wqb + nw;                // 2MB each
    ushort_t* Wob = Wkb + nw;
    ushort_t* Wvb = Wob + nw;
    int*      cidx   = (int*)(Wvb + nw);     // 32KB
    int*      nvalid = cidx + 4 * S_LEN;
    int*      npads  = nvalid + 4;           // total ~105MB

    ushort_t* Kc = Xhi;                      // compact bf16 key rows
    ushort_t* Vc = Xlo;                      // compact bf16 value rows

    scan_mask<<<dim3(4), 64, 0, stream>>>(mask, cidx, nvalid, npads);
    prep_gather<<<dim3(CONVB + M), 256, 0, stream>>>(
        query, Wq, Wk, Wo, Wv, key, value, cidx, nvalid,
        Qbf, Wqb, Wkb, Wob, Wvb, Kc, Vc, Mbc);

    const float SC2 = 0.125f * LOG2E;
    proj_fused<<<dim3(1536), 256, 0, stream>>>(
        Qbf, Kc, Wvb, Vc, Wqb, Wkb, bq, bk, bv, npads, Qb, Kb, Vtg, SC2);

    flash_attn_bf16<<<dim3((S_LEN / QBLK) * B * NHEADS), 256, 0, stream>>>(
        Qb, Kb, Vtg, Mbc, npads, Xhi, Xlo);

    gemm_out<<<dim3(HID_C / 128, M / 128), 256, 0, stream>>>(
        Xhi, Xlo, Wob, bo, out, M, HID_C, HID_C);
}

// Round 20
// 194.560 us; speedup vs baseline: 1.0616x; 1.0247x over previous
//
#include <hip/hip_runtime.h>
#include <cstddef>
#include <math.h>

#define S_LEN  2048
#define HID_C  1024
#define NHEADS 16
#define HDIM   64

typedef __attribute__((ext_vector_type(8))) short bf16x8;
typedef __attribute__((ext_vector_type(4))) float f32x4;
typedef __attribute__((ext_vector_type(16))) float f32x16;
typedef unsigned short ushort_t;

#define LOG2E 1.44269504088896f

__device__ __forceinline__ unsigned short f32_to_bf16_rn(float f) {
    unsigned int u = __float_as_uint(f);
    return (unsigned short)((u + 0x8000u) >> 16);
}

// raw hardware exp2: one v_exp_f32 (vs exp2f's multi-instruction ocml call)
__device__ __forceinline__ float fexp2(float x) {
    float r;
    asm("v_exp_f32 %0, %1" : "=v"(r) : "v"(x));
    return r;
}

// direct global->LDS 16B copy (lds dest = wave-uniform base + lane*16)
__device__ __forceinline__ void gload16(const ushort_t* g, ushort_t* l) {
    __builtin_amdgcn_global_load_lds(
        (const __attribute__((address_space(1))) void*)g,
        (__attribute__((address_space(3))) void*)l, 16, 0, 0);
}

// balanced tree reductions over f32x16 (depth 5; max3-fusable)
__device__ __forceinline__ float tmax16(const f32x16& v) {
    float a0 = fmaxf(v[0], v[1]),   a1 = fmaxf(v[2], v[3]);
    float a2 = fmaxf(v[4], v[5]),   a3 = fmaxf(v[6], v[7]);
    float a4 = fmaxf(v[8], v[9]),   a5 = fmaxf(v[10], v[11]);
    float a6 = fmaxf(v[12], v[13]), a7 = fmaxf(v[14], v[15]);
    float b0 = fmaxf(a0, a1), b1 = fmaxf(a2, a3);
    float b2 = fmaxf(a4, a5), b3 = fmaxf(a6, a7);
    return fmaxf(fmaxf(b0, b1), fmaxf(b2, b3));
}
__device__ __forceinline__ float tsum16(const f32x16& v) {
    float a0 = v[0] + v[1],   a1 = v[2] + v[3];
    float a2 = v[4] + v[5],   a3 = v[6] + v[7];
    float a4 = v[8] + v[9],   a5 = v[10] + v[11];
    float a6 = v[12] + v[13], a7 = v[14] + v[15];
    float b0 = a0 + a1, b1 = a2 + a3, b2 = a4 + a5, b3 = a6 + a7;
    return (b0 + b1) + (b2 + b3);
}

// ---------------------------------------------------------------------------
// scan: order-preserving compaction of valid key indices per batch.
// ---------------------------------------------------------------------------
__global__ void scan_mask(const int* __restrict__ mask, int* __restrict__ cidx,
                          int* __restrict__ nvalid, int* __restrict__ npads) {
    const int b = blockIdx.x;
    const int lane = threadIdx.x;           // blockDim.x == 64
    int base = 0;
    for (int i = 0; i < S_LEN / 64; ++i) {
        const int s = i * 64 + lane;
        const int v = mask[b * S_LEN + s];
        const unsigned long long bal = __ballot(v != 0);
        const int pre = __popcll(bal & ((1ull << lane) - 1ull));
        if (v) cidx[b * S_LEN + base + pre] = s;
        base += (int)__popcll(bal);
    }
    if (lane == 0) { nvalid[b] = base; npads[b] = (base + 63) & ~63; }
}

// ---------------------------------------------------------------------------
// fused prep + gather (unchanged)
// ---------------------------------------------------------------------------
#define CONVB 12288

__global__ void prep_gather(
    const float* __restrict__ query,
    const float* __restrict__ Wq, const float* __restrict__ Wk,
    const float* __restrict__ Wo, const float* __restrict__ Wv,
    const float* __restrict__ key, const float* __restrict__ value,
    const int* __restrict__ cidx, const int* __restrict__ nvalid,
    ushort_t* __restrict__ Qbf, ushort_t* __restrict__ Wqb,
    ushort_t* __restrict__ Wkb, ushort_t* __restrict__ Wob,
    ushort_t* __restrict__ Wvb,
    ushort_t* __restrict__ Kc, ushort_t* __restrict__ Vc,
    float* __restrict__ Mbc)
{
    if (blockIdx.x < CONVB) {
        const unsigned SEG = 4u * S_LEN * HID_C;
        const unsigned NW = HID_C * HID_C;
        unsigned i = (blockIdx.x * 256u + threadIdx.x) * 4u;
        const float* src; ushort_t* dst;
        if (i < SEG) { src = query; dst = Qbf; }
        else {
            i -= SEG;
            if (i < NW) { src = Wq; dst = Wqb; }
            else { i -= NW;
                if (i < NW) { src = Wk; dst = Wkb; }
                else { i -= NW;
                    if (i < NW) { src = Wo; dst = Wob; }
                    else { i -= NW; if (i >= NW) return; src = Wv; dst = Wvb; }
                }
            }
        }
        float4 v = *reinterpret_cast<const float4*>(src + i);
        uint2 p;
        p.x = ((unsigned)f32_to_bf16_rn(v.y) << 16) | f32_to_bf16_rn(v.x);
        p.y = ((unsigned)f32_to_bf16_rn(v.w) << 16) | f32_to_bf16_rn(v.z);
        *reinterpret_cast<uint2*>(dst + i) = p;
    } else {
        const int r = blockIdx.x - CONVB;       // 0..8191 compact row
        const int b = r >> 11, j = r & 2047;
        const int tid = threadIdx.x;
        const int nv = nvalid[b];
        if (tid == 0) Mbc[r] = (j < nv) ? 0.f : -1e30f;
        const int np128 = (nv + 127) & ~127;
        if (j >= np128) return;
        uint2* kd = reinterpret_cast<uint2*>(Kc + (size_t)r * HID_C + tid * 4);
        uint2* vd = reinterpret_cast<uint2*>(Vc + (size_t)r * HID_C + tid * 4);
        if (j < nv) {
            const int src = cidx[b * S_LEN + j];
            const float4 kv = *reinterpret_cast<const float4*>(
                key + ((size_t)b * S_LEN + src) * HID_C + tid * 4);
            const float4 vv = *reinterpret_cast<const float4*>(
                value + ((size_t)b * S_LEN + src) * HID_C + tid * 4);
            uint2 kp, vp;
            kp.x = ((unsigned)f32_to_bf16_rn(kv.y) << 16) | f32_to_bf16_rn(kv.x);
            kp.y = ((unsigned)f32_to_bf16_rn(kv.w) << 16) | f32_to_bf16_rn(kv.z);
            vp.x = ((unsigned)f32_to_bf16_rn(vv.y) << 16) | f32_to_bf16_rn(vv.x);
            vp.y = ((unsigned)f32_to_bf16_rn(vv.w) << 16) | f32_to_bf16_rn(vv.z);
            *kd = kp; *vd = vp;
        } else {
            *kd = make_uint2(0u, 0u); *vd = make_uint2(0u, 0u);
        }
    }
}

// ---------------------------------------------------------------------------
// shared GEMM core, BK=32 (measured-best R17 config).
// LDS linear [512 slots x 16B]; slot s holds (r=s>>2, kq=(s&3)^((s>>3)&3));
// fragment read slot = r*4 + (kq ^ ((r>>1)&3)).
// ---------------------------------------------------------------------------
__device__ __forceinline__ void gemm_core(
    const ushort_t* __restrict__ Ab, const ushort_t* __restrict__ Wb,
    const float* __restrict__ bias, ushort_t* __restrict__ outB,
    int bm, int bn, int N, int K, float oscale, bool rowBias,
    ushort_t* Ah, ushort_t* Bh)
{
    const int tid  = threadIdx.x;
    const int lane = tid & 63;
    const int wave = tid >> 6;
    const int wm = (wave >> 1) * 64;
    const int wn = (wave & 1) * 64;
    const int fr = lane & 15;
    const int kq = lane >> 4;

    int srow[2], skq[2];
#pragma unroll
    for (int i = 0; i < 2; ++i) {
        const int s = i * 256 + tid;
        srow[i] = s >> 2;
        skq[i] = (s & 3) ^ ((s >> 3) & 3);
    }
    const int wslot = tid & 192;

    f32x4 acc[4][4];
#pragma unroll
    for (int i = 0; i < 4; ++i)
#pragma unroll
        for (int j = 0; j < 4; ++j)
#pragma unroll
            for (int r = 0; r < 4; ++r) acc[i][j][r] = 0.f;

    for (int k0 = 0; k0 < K; k0 += 32) {
        __syncthreads();
#pragma unroll
        for (int i = 0; i < 2; ++i) {
            const int sb = (i * 256 + wslot) * 8;
            gload16(Ab + (size_t)(bm + srow[i]) * K + k0 + skq[i] * 8, Ah + sb);
            gload16(Wb + (size_t)(bn + srow[i]) * K + k0 + skq[i] * 8, Bh + sb);
        }
        __syncthreads();

        bf16x8 fah[4], fbh[4];
#pragma unroll
        for (int mi = 0; mi < 4; ++mi) {
            const int rr = wm + mi * 16 + fr;
            fah[mi] = *reinterpret_cast<const bf16x8*>(
                Ah + (rr * 4 + (kq ^ ((rr >> 1) & 3))) * 8);
        }
#pragma unroll
        for (int ni = 0; ni < 4; ++ni) {
            const int rr = wn + ni * 16 + fr;
            fbh[ni] = *reinterpret_cast<const bf16x8*>(
                Bh + (rr * 4 + (kq ^ ((rr >> 1) & 3))) * 8);
        }

#pragma unroll
        for (int mi = 0; mi < 4; ++mi)
#pragma unroll
            for (int ni = 0; ni < 4; ++ni)
                acc[mi][ni] = __builtin_amdgcn_mfma_f32_16x16x32_bf16(
                    fah[mi], fbh[ni], acc[mi][ni], 0, 0, 0);
    }

    const int fq = lane >> 4;
    if (rowBias) {
#pragma unroll
        for (int mi = 0; mi < 4; ++mi)
#pragma unroll
            for (int r = 0; r < 4; ++r) {
                const int row = bm + wm + mi * 16 + fq * 4 + r;
                const float bvr = bias[row];
#pragma unroll
                for (int ni = 0; ni < 4; ++ni)
                    outB[(size_t)row * N + bn + wn + ni * 16 + fr] =
                        f32_to_bf16_rn((acc[mi][ni][r] + bvr) * oscale);
            }
    } else {
        float bv[4];
#pragma unroll
        for (int ni = 0; ni < 4; ++ni) bv[ni] = bias[bn + wn + ni * 16 + fr];
#pragma unroll
        for (int mi = 0; mi < 4; ++mi)
#pragma unroll
            for (int ni = 0; ni < 4; ++ni) {
                const size_t rowb = (size_t)(bm + wm + mi * 16 + fq * 4);
                const int col = bn + wn + ni * 16 + fr;
#pragma unroll
                for (int r = 0; r < 4; ++r)
                    outB[(rowb + r) * N + col] =
                        f32_to_bf16_rn((acc[mi][ni][r] + bv[ni]) * oscale);
            }
    }
}

// ---------------------------------------------------------------------------
// fused Q/K/V^T projections, R20: XCD-affinity swizzle for Q and K sections.
// Decode n -> (x=n&7, bn=(n>>3)&7, bm=((n>>6)<<3)|x): all 8 blocks sharing an
// A-panel (same bm) land on XCD bm&7 -> per-XCD A set 2MB + W 2MB fits L2.
// V^T section keeps natural order (its big operand Vc is indexed by bn; the
// 8 sharing blocks differ by 64 ≡ 0 mod 8 -> already same-XCD).
// ---------------------------------------------------------------------------
__global__ __launch_bounds__(256) void proj_fused(
    const ushort_t* __restrict__ Qbf, const ushort_t* __restrict__ Kc,
    const ushort_t* __restrict__ Wvb, const ushort_t* __restrict__ Vc,
    const ushort_t* __restrict__ Wqb, const ushort_t* __restrict__ Wkb,
    const float* __restrict__ bq, const float* __restrict__ bk,
    const float* __restrict__ bv, const int* __restrict__ npads,
    ushort_t* __restrict__ Qb, ushort_t* __restrict__ Kb,
    ushort_t* __restrict__ Vtg, float sc2)
{
    __shared__ __align__(16) ushort_t Ah[128 * 32];
    __shared__ __align__(16) ushort_t Bh[128 * 32];

    int id = blockIdx.x;
    if (id < 512) {
        const int bm = (((id >> 6) << 3) | (id & 7)) * 128;
        const int bn = ((id >> 3) & 7) * 128;
        gemm_core(Qbf, Wqb, bq, Qb, bm, bn, HID_C, HID_C, sc2, false, Ah, Bh);
    } else if (id < 1024) {
        id -= 512;
        const int bm = (((id >> 6) << 3) | (id & 7)) * 128;
        const int bn = ((id >> 3) & 7) * 128;
        if ((bm & 2047) >= npads[bm >> 11]) return;
        gemm_core(Kc, Wkb, bk, Kb, bm, bn, HID_C, HID_C, 1.f, false, Ah, Bh);
    } else {
        id -= 1024;
        const int bn = (id & 63) * 128;
        if ((bn & 2047) >= npads[bn >> 11]) return;
        gemm_core(Wvb, Vc, bv, Vtg, (id >> 6) * 128, bn,
                  4 * S_LEN, HID_C, 1.f, true, Ah, Bh);
    }
}

// ---------------------------------------------------------------------------
// O-GEMM: fp32 out, split-A (hi/lo, 2 MFMA), BK=32, 1D grid with the same
// XCD-affinity decode (A-panels Xhi/Xlo shared across bn -> same XCD).
// ---------------------------------------------------------------------------
__global__ __launch_bounds__(256) void gemm_out(
    const ushort_t* __restrict__ Xhi, const ushort_t* __restrict__ Xlo,
    const ushort_t* __restrict__ Wb, const float* __restrict__ bias,
    float* __restrict__ outF, int M, int N, int K)
{
    __shared__ __align__(16) ushort_t Ah[128 * 32];
    __shared__ __align__(16) ushort_t Al[128 * 32];
    __shared__ __align__(16) ushort_t Bh[128 * 32];

    const int n = blockIdx.x;
    const int bm = ((((n >> 6) << 3) | (n & 7))) * 128;
    const int bn = ((n >> 3) & 7) * 128;

    const int tid  = threadIdx.x;
    const int lane = tid & 63;
    const int wave = tid >> 6;
    const int wm = (wave >> 1) * 64;
    const int wn = (wave & 1) * 64;
    const int fr = lane & 15;
    const int kq = lane >> 4;

    int srow[2], skq[2];
#pragma unroll
    for (int i = 0; i < 2; ++i) {
        const int s = i * 256 + tid;
        srow[i] = s >> 2;
        skq[i] = (s & 3) ^ ((s >> 3) & 3);
    }
    const int wslot = tid & 192;

    f32x4 acc[4][4];
#pragma unroll
    for (int i = 0; i < 4; ++i)
#pragma unroll
        for (int j = 0; j < 4; ++j)
#pragma unroll
            for (int r = 0; r < 4; ++r) acc[i][j][r] = 0.f;

    for (int k0 = 0; k0 < K; k0 += 32) {
        __syncthreads();
#pragma unroll
        for (int i = 0; i < 2; ++i) {
            const int sb = (i * 256 + wslot) * 8;
            const size_t ga = (size_t)(bm + srow[i]) * K + k0 + skq[i] * 8;
            gload16(Xhi + ga, Ah + sb);
            gload16(Xlo + ga, Al + sb);
            gload16(Wb + (size_t)(bn + srow[i]) * K + k0 + skq[i] * 8, Bh + sb);
        }
        __syncthreads();

        bf16x8 fah[4], fal[4], fbh[4];
#pragma unroll
        for (int mi = 0; mi < 4; ++mi) {
            const int rr = wm + mi * 16 + fr;
            const int sl = (rr * 4 + (kq ^ ((rr >> 1) & 3))) * 8;
            fah[mi] = *reinterpret_cast<const bf16x8*>(Ah + sl);
            fal[mi] = *reinterpret_cast<const bf16x8*>(Al + sl);
        }
#pragma unroll
        for (int ni = 0; ni < 4; ++ni) {
            const int rr = wn + ni * 16 + fr;
            fbh[ni] = *reinterpret_cast<const bf16x8*>(
                Bh + (rr * 4 + (kq ^ ((rr >> 1) & 3))) * 8);
        }

#pragma unroll
        for (int mi = 0; mi < 4; ++mi)
#pragma unroll
            for (int ni = 0; ni < 4; ++ni) {
                acc[mi][ni] = __builtin_amdgcn_mfma_f32_16x16x32_bf16(
                    fah[mi], fbh[ni], acc[mi][ni], 0, 0, 0);
                acc[mi][ni] = __builtin_amdgcn_mfma_f32_16x16x32_bf16(
                    fal[mi], fbh[ni], acc[mi][ni], 0, 0, 0);
            }
    }

    const int fq = lane >> 4;
    float bv[4];
#pragma unroll
    for (int ni = 0; ni < 4; ++ni) bv[ni] = bias[bn + wn + ni * 16 + fr];
#pragma unroll
    for (int mi = 0; mi < 4; ++mi)
#pragma unroll
        for (int ni = 0; ni < 4; ++ni) {
            const size_t rowb = (size_t)(bm + wm + mi * 16 + fq * 4);
            const int col = bn + wn + ni * 16 + fr;
#pragma unroll
            for (int r = 0; r < 4; ++r)
                outF[(rowb + r) * N + col] = acc[mi][ni][r] + bv[ni];
        }
}

// ---------------------------------------------------------------------------
// Flash attention — EXACT measured-best R17 kernel (80µs).
// ---------------------------------------------------------------------------
#define QBLK 128
#define KVB  64
#define LDA  72

__global__ __launch_bounds__(256) void flash_attn_bf16(
    const ushort_t* __restrict__ Qb, const ushort_t* __restrict__ Kb,
    const ushort_t* __restrict__ Vtg, const float* __restrict__ maskb,
    const int* __restrict__ npads,
    ushort_t* __restrict__ Xhi, ushort_t* __restrict__ Xlo)
{
    __shared__ __align__(16) ushort_t Ks[KVB * LDA];
    __shared__ __align__(16) ushort_t Vt[HDIM * LDA];
    __shared__ float Xpose[QBLK];

    const int n  = blockIdx.x;
    const int bh = (n & 7) * 8 + ((n >> 3) & 7);
    const int qx = n >> 6;
    const int b  = bh >> 4;
    const int h  = bh & 15;
    const int q0 = qx * QBLK;

    const int tid  = threadIdx.x;
    const int lane = tid & 63;
    const int w    = tid >> 6;
    const int lq = lane & 31;
    const int lh = lane >> 5;

    const size_t bS = (size_t)b * S_LEN;
    const int hc = h * HDIM;
    const int npad = npads[b];

    bf16x8 qf[4];
#pragma unroll
    for (int s = 0; s < 4; ++s)
        qf[s] = *reinterpret_cast<const bf16x8*>(
            &Qb[(bS + q0 + w * 32 + lq) * HID_C + hc + s * 16 + lh * 8]);

    f32x16 OV[2], zc;
#pragma unroll
    for (int r = 0; r < 16; ++r) { OV[0][r] = 0.f; OV[1][r] = 0.f; zc[r] = 0.f; }
    float m_ = -1e30f, l_ = 0.f;

    const int sr  = tid >> 2;
    const int seg = tid & 3;
    const ushort_t* kbase = &Kb[(bS + sr) * HID_C + hc + seg * 16];
    const ushort_t* vbase = &Vtg[(size_t)(hc + sr) * (4 * S_LEN) + bS + seg * 16];

    {
        bf16x8 kv0 = *reinterpret_cast<const bf16x8*>(kbase);
        bf16x8 kv1 = *reinterpret_cast<const bf16x8*>(kbase + 8);
        bf16x8 vv0 = *reinterpret_cast<const bf16x8*>(vbase);
        bf16x8 vv1 = *reinterpret_cast<const bf16x8*>(vbase + 8);
        *reinterpret_cast<bf16x8*>(&Ks[sr * LDA + seg * 16])     = kv0;
        *reinterpret_cast<bf16x8*>(&Ks[sr * LDA + seg * 16 + 8]) = kv1;
        *reinterpret_cast<bf16x8*>(&Vt[sr * LDA + seg * 16])     = vv0;
        *reinterpret_cast<bf16x8*>(&Vt[sr * LDA + seg * 16 + 8]) = vv1;
        __syncthreads();
    }

    for (int t = 0; t < npad; t += KVB) {
        // ---- QK^T (swapped, 32x32x16), zero-C first MFMA ----
        f32x16 S[2];
        __builtin_amdgcn_s_setprio(1);
#pragma unroll
        for (int kt = 0; kt < 2; ++kt) {
            bf16x8 kf0 = *reinterpret_cast<const bf16x8*>(
                &Ks[(kt * 32 + lq) * LDA + lh * 8]);
            S[kt] = __builtin_amdgcn_mfma_f32_32x32x16_bf16(kf0, qf[0], zc, 0, 0, 0);
#pragma unroll
            for (int s = 1; s < 4; ++s) {
                bf16x8 kf = *reinterpret_cast<const bf16x8*>(
                    &Ks[(kt * 32 + lq) * LDA + s * 16 + lh * 8]);
                S[kt] = __builtin_amdgcn_mfma_f32_32x32x16_bf16(
                    kf, qf[s], S[kt], 0, 0, 0);
            }
        }
        __builtin_amdgcn_s_setprio(0);

        // ---- T14: issue next-tile K/V loads ----
        const bool more = (t + KVB < npad);
        bf16x8 kv0n, kv1n, vv0n, vv1n;
        if (more) {
            const ushort_t* kp = kbase + (size_t)(t + KVB) * HID_C;
            const ushort_t* vp = vbase + (t + KVB);
            kv0n = *reinterpret_cast<const bf16x8*>(kp);
            kv1n = *reinterpret_cast<const bf16x8*>(kp + 8);
            vv0n = *reinterpret_cast<const bf16x8*>(vp);
            vv1n = *reinterpret_cast<const bf16x8*>(vp + 8);
        }

        // ---- mask bias: only the FINAL tile can contain padded keys ----
        if (!more) {
#pragma unroll
            for (int kt = 0; kt < 2; ++kt)
#pragma unroll
                for (int g = 0; g < 4; ++g) {
                    float4 mv = *reinterpret_cast<const float4*>(
                        &maskb[bS + t + kt * 32 + g * 8 + lh * 4]);
#pragma unroll
                    for (int e = 0; e < 4; ++e)
                        S[kt][g * 4 + e] += reinterpret_cast<const float*>(&mv)[e];
                }
        }

        // ---- tree row-max (one q per lane) ----
        float mx = fmaxf(tmax16(S[0]), tmax16(S[1]));
        mx = fmaxf(mx, __shfl_xor(mx, 32));

        // ---- defer-max (rare rescale) ----
        if (!__all(mx <= m_ + 8.f)) {
            float mn = fmaxf(m_, mx);
            float corr = fexp2(m_ - mn);
            m_ = mn; l_ *= corr;
            if (lh == 0) Xpose[w * 32 + lq] = corr;   // same-wave RAW
#pragma unroll
            for (int r = 0; r < 16; ++r) {
                float cq = Xpose[w * 32 + (r & 3) + 8 * (r >> 2) + 4 * lh];
                OV[0][r] *= cq;
                OV[1][r] *= cq;
            }
        }

        // ---- P = exp2(S - m) via raw v_exp_f32, tree row-sum ----
#pragma unroll
        for (int kt = 0; kt < 2; ++kt)
#pragma unroll
            for (int r = 0; r < 16; ++r) S[kt][r] = fexp2(S[kt][r] - m_);
        float ls = tsum16(S[0]) + tsum16(S[1]);
        ls += __shfl_xor(ls, 32);
        l_ += ls;

        // ---- P -> PV A-frags in registers (cvt_pk + permlane32_swap) ----
        bf16x8 pa[4];
#pragma unroll
        for (int kt = 0; kt < 2; ++kt)
#pragma unroll
            for (int u = 0; u < 2; ++u) {
                const int bb = u * 8;
                unsigned int c0, c1, c2, c3;
                asm("v_cvt_pk_bf16_f32 %0, %1, %2"
                    : "=v"(c0) : "v"(S[kt][bb + 0]), "v"(S[kt][bb + 1]));
                asm("v_cvt_pk_bf16_f32 %0, %1, %2"
                    : "=v"(c1) : "v"(S[kt][bb + 2]), "v"(S[kt][bb + 3]));
                asm("v_cvt_pk_bf16_f32 %0, %1, %2"
                    : "=v"(c2) : "v"(S[kt][bb + 4]), "v"(S[kt][bb + 5]));
                asm("v_cvt_pk_bf16_f32 %0, %1, %2"
                    : "=v"(c3) : "v"(S[kt][bb + 6]), "v"(S[kt][bb + 7]));
                asm("v_permlane32_swap_b32 %0, %1" : "+v"(c0), "+v"(c2));
                asm("v_permlane32_swap_b32 %0, %1" : "+v"(c1), "+v"(c3));
                uint4 wv = make_uint4(c0, c1, c2, c3);
                pa[kt * 2 + u] = *reinterpret_cast<bf16x8*>(&wv);
            }

        // ---- PV (32x32x16) ----
        __builtin_amdgcn_s_setprio(1);
#pragma unroll
        for (int dt = 0; dt < 2; ++dt)
#pragma unroll
            for (int f = 0; f < 4; ++f) {
                bf16x8 vf = *reinterpret_cast<const bf16x8*>(
                    &Vt[(dt * 32 + lq) * LDA + f * 16 + lh * 8]);
                OV[dt] = __builtin_amdgcn_mfma_f32_32x32x16_bf16(
                    pa[f], vf, OV[dt], 0, 0, 0);
            }
        __builtin_amdgcn_s_setprio(0);

        // ---- stage next tile ----
        __syncthreads();
        if (more) {
            *reinterpret_cast<bf16x8*>(&Ks[sr * LDA + seg * 16])     = kv0n;
            *reinterpret_cast<bf16x8*>(&Ks[sr * LDA + seg * 16 + 8]) = kv1n;
            *reinterpret_cast<bf16x8*>(&Vt[sr * LDA + seg * 16])     = vv0n;
            *reinterpret_cast<bf16x8*>(&Vt[sr * LDA + seg * 16 + 8]) = vv1n;
            __syncthreads();
        }
    }

    // ---- epilogue: x = OV/l, pre-split hi/lo bf16 ----
    if (lh == 0) Xpose[w * 32 + lq] = 1.f / l_;   // same-wave RAW
#pragma unroll
    for (int r = 0; r < 16; ++r) {
        const int qr = (r & 3) + 8 * (r >> 2) + 4 * lh;
        const float inv = Xpose[w * 32 + qr];
        const size_t row = bS + q0 + w * 32 + qr;
#pragma unroll
        for (int dt = 0; dt < 2; ++dt) {
            float v = OV[dt][r] * inv;
            unsigned int u = __float_as_uint(v);
            unsigned short hi = (unsigned short)(u >> 16);
            float res = v - __uint_as_float(u & 0xFFFF0000u);
            Xhi[row * HID_C + hc + dt * 32 + lq] = hi;
            Xlo[row * HID_C + hc + dt * 32 + lq] = f32_to_bf16_rn(res);
        }
    }
}

// ---------------------------------------------------------------------------
extern "C" void kernel_launch(void* const* d_in, const int* in_sizes, int n_in,
                              void* d_out, int out_size, void* d_ws, size_t ws_size,
                              hipStream_t stream) {
    const float* query = (const float*)d_in[0];
    const float* key   = (const float*)d_in[1];
    const float* value = (const float*)d_in[2];
    const int*   mask  = (const int*)d_in[3];
    const float* Wq = (const float*)d_in[4];
    const float* bq = (const float*)d_in[5];
    const float* Wk = (const float*)d_in[6];
    const float* bk = (const float*)d_in[7];
    const float* Wv = (const float*)d_in[8];
    const float* bv = (const float*)d_in[9];
    const float* Wo = (const float*)d_in[10];
    const float* bo = (const float*)d_in[11];
    float* out = (float*)d_out;

    const int B = 4, M = B * S_LEN;          // 8192
    const size_t seg = (size_t)M * HID_C;
    const size_t nw  = (size_t)HID_C * HID_C;

    ushort_t* Qb  = (ushort_t*)d_ws;         // 16MB each
    ushort_t* Kb  = Qb + seg;
    ushort_t* Vtg = Kb + seg;                // V^T: [1024 feat][8192 compact tok]
    ushort_t* Xhi = Vtg + seg;               // aliased: Kc before attn
    ushort_t* Xlo = Xhi + seg;               // aliased: Vc before attn
    ushort_t* Qbf = Xlo + seg;               // query bf16
    float*    Mbc = (float*)(Qbf + seg);     // 32KB compact mask bias
    ushort_t* Wqb = (ushort_t*)(Mbc + 4 * S_LEN);
    ushort_t* Wkb = Wqb + nw;                // 2MB each
    ushort_t* Wob = Wkb + nw;
    ushort_t* Wvb = Wob + nw;
    int*      cidx   = (int*)(Wvb + nw);     // 32KB
    int*      nvalid = cidx + 4 * S_LEN;
    int*      npads  = nvalid + 4;           // total ~105MB

    ushort_t* Kc = Xhi;                      // compact bf16 key rows
    ushort_t* Vc = Xlo;                      // compact bf16 value rows

    scan_mask<<<dim3(4), 64, 0, stream>>>(mask, cidx, nvalid, npads);
    prep_gather<<<dim3(CONVB + M), 256, 0, stream>>>(
        query, Wq, Wk, Wo, Wv, key, value, cidx, nvalid,
        Qbf, Wqb, Wkb, Wob, Wvb, Kc, Vc, Mbc);

    const float SC2 = 0.125f * LOG2E;
    proj_fused<<<dim3(1536), 256, 0, stream>>>(
        Qbf, Kc, Wvb, Vc, Wqb, Wkb, bq, bk, bv, npads, Qb, Kb, Vtg, SC2);

    flash_attn_bf16<<<dim3((S_LEN / QBLK) * B * NHEADS), 256, 0, stream>>>(
        Qb, Kb, Vtg, Mbc, npads, Xhi, Xlo);

    gemm_out<<<dim3(512), 256, 0, stream>>>(
        Xhi, Xlo, Wob, bo, out, M, HID_C, HID_C);
}

// Round 21
// 180.053 us; speedup vs baseline: 1.1471x; 1.0806x over previous
//
#include <hip/hip_runtime.h>
#include <cstddef>
#include <math.h>

#define S_LEN  2048
#define HID_C  1024
#define NHEADS 16
#define HDIM   64

typedef __attribute__((ext_vector_type(8))) short bf16x8;
typedef __attribute__((ext_vector_type(4))) float f32x4;
typedef __attribute__((ext_vector_type(16))) float f32x16;
typedef unsigned short ushort_t;

#define LOG2E 1.44269504088896f

__device__ __forceinline__ unsigned short f32_to_bf16_rn(float f) {
    unsigned int u = __float_as_uint(f);
    return (unsigned short)((u + 0x8000u) >> 16);
}

// raw hardware exp2: one v_exp_f32 (vs exp2f's multi-instruction ocml call)
__device__ __forceinline__ float fexp2(float x) {
    float r;
    asm("v_exp_f32 %0, %1" : "=v"(r) : "v"(x));
    return r;
}

// direct global->LDS 16B copy (lds dest = wave-uniform base + lane*16)
__device__ __forceinline__ void gload16(const ushort_t* g, ushort_t* l) {
    __builtin_amdgcn_global_load_lds(
        (const __attribute__((address_space(1))) void*)g,
        (__attribute__((address_space(3))) void*)l, 16, 0, 0);
}

// balanced tree reductions over f32x16 (depth 5; max3-fusable)
__device__ __forceinline__ float tmax16(const f32x16& v) {
    float a0 = fmaxf(v[0], v[1]),   a1 = fmaxf(v[2], v[3]);
    float a2 = fmaxf(v[4], v[5]),   a3 = fmaxf(v[6], v[7]);
    float a4 = fmaxf(v[8], v[9]),   a5 = fmaxf(v[10], v[11]);
    float a6 = fmaxf(v[12], v[13]), a7 = fmaxf(v[14], v[15]);
    float b0 = fmaxf(a0, a1), b1 = fmaxf(a2, a3);
    float b2 = fmaxf(a4, a5), b3 = fmaxf(a6, a7);
    return fmaxf(fmaxf(b0, b1), fmaxf(b2, b3));
}
__device__ __forceinline__ float tsum16(const f32x16& v) {
    float a0 = v[0] + v[1],   a1 = v[2] + v[3];
    float a2 = v[4] + v[5],   a3 = v[6] + v[7];
    float a4 = v[8] + v[9],   a5 = v[10] + v[11];
    float a6 = v[12] + v[13], a7 = v[14] + v[15];
    float b0 = a0 + a1, b1 = a2 + a3, b2 = a4 + a5, b3 = a6 + a7;
    return (b0 + b1) + (b2 + b3);
}

// ---------------------------------------------------------------------------
// scan: order-preserving compaction of valid key indices per batch.
// ---------------------------------------------------------------------------
__global__ void scan_mask(const int* __restrict__ mask, int* __restrict__ cidx,
                          int* __restrict__ nvalid, int* __restrict__ npads) {
    const int b = blockIdx.x;
    const int lane = threadIdx.x;           // blockDim.x == 64
    int base = 0;
    for (int i = 0; i < S_LEN / 64; ++i) {
        const int s = i * 64 + lane;
        const int v = mask[b * S_LEN + s];
        const unsigned long long bal = __ballot(v != 0);
        const int pre = __popcll(bal & ((1ull << lane) - 1ull));
        if (v) cidx[b * S_LEN + base + pre] = s;
        base += (int)__popcll(bal);
    }
    if (lane == 0) { nvalid[b] = base; npads[b] = (base + 63) & ~63; }
}

// ---------------------------------------------------------------------------
// fused prep + gather (unchanged)
// ---------------------------------------------------------------------------
#define CONVB 12288

__global__ void prep_gather(
    const float* __restrict__ query,
    const float* __restrict__ Wq, const float* __restrict__ Wk,
    const float* __restrict__ Wo, const float* __restrict__ Wv,
    const float* __restrict__ key, const float* __restrict__ value,
    const int* __restrict__ cidx, const int* __restrict__ nvalid,
    ushort_t* __restrict__ Qbf, ushort_t* __restrict__ Wqb,
    ushort_t* __restrict__ Wkb, ushort_t* __restrict__ Wob,
    ushort_t* __restrict__ Wvb,
    ushort_t* __restrict__ Kc, ushort_t* __restrict__ Vc,
    float* __restrict__ Mbc)
{
    if (blockIdx.x < CONVB) {
        const unsigned SEG = 4u * S_LEN * HID_C;
        const unsigned NW = HID_C * HID_C;
        unsigned i = (blockIdx.x * 256u + threadIdx.x) * 4u;
        const float* src; ushort_t* dst;
        if (i < SEG) { src = query; dst = Qbf; }
        else {
            i -= SEG;
            if (i < NW) { src = Wq; dst = Wqb; }
            else { i -= NW;
                if (i < NW) { src = Wk; dst = Wkb; }
                else { i -= NW;
                    if (i < NW) { src = Wo; dst = Wob; }
                    else { i -= NW; if (i >= NW) return; src = Wv; dst = Wvb; }
                }
            }
        }
        float4 v = *reinterpret_cast<const float4*>(src + i);
        uint2 p;
        p.x = ((unsigned)f32_to_bf16_rn(v.y) << 16) | f32_to_bf16_rn(v.x);
        p.y = ((unsigned)f32_to_bf16_rn(v.w) << 16) | f32_to_bf16_rn(v.z);
        *reinterpret_cast<uint2*>(dst + i) = p;
    } else {
        const int r = blockIdx.x - CONVB;       // 0..8191 compact row
        const int b = r >> 11, j = r & 2047;
        const int tid = threadIdx.x;
        const int nv = nvalid[b];
        if (tid == 0) Mbc[r] = (j < nv) ? 0.f : -1e30f;
        const int np128 = (nv + 127) & ~127;
        if (j >= np128) return;
        uint2* kd = reinterpret_cast<uint2*>(Kc + (size_t)r * HID_C + tid * 4);
        uint2* vd = reinterpret_cast<uint2*>(Vc + (size_t)r * HID_C + tid * 4);
        if (j < nv) {
            const int src = cidx[b * S_LEN + j];
            const float4 kv = *reinterpret_cast<const float4*>(
                key + ((size_t)b * S_LEN + src) * HID_C + tid * 4);
            const float4 vv = *reinterpret_cast<const float4*>(
                value + ((size_t)b * S_LEN + src) * HID_C + tid * 4);
            uint2 kp, vp;
            kp.x = ((unsigned)f32_to_bf16_rn(kv.y) << 16) | f32_to_bf16_rn(kv.x);
            kp.y = ((unsigned)f32_to_bf16_rn(kv.w) << 16) | f32_to_bf16_rn(kv.z);
            vp.x = ((unsigned)f32_to_bf16_rn(vv.y) << 16) | f32_to_bf16_rn(vv.x);
            vp.y = ((unsigned)f32_to_bf16_rn(vv.w) << 16) | f32_to_bf16_rn(vv.z);
            *kd = kp; *vd = vp;
        } else {
            *kd = make_uint2(0u, 0u); *vd = make_uint2(0u, 0u);
        }
    }
}

// ---------------------------------------------------------------------------
// shared GEMM core, BK=32 (measured-best config).
// ---------------------------------------------------------------------------
__device__ __forceinline__ void gemm_core(
    const ushort_t* __restrict__ Ab, const ushort_t* __restrict__ Wb,
    const float* __restrict__ bias, ushort_t* __restrict__ outB,
    float* __restrict__ outF,
    int bm, int bn, int N, int K, float oscale, int omode,
    ushort_t* Ah, ushort_t* Bh)
{
    const int tid  = threadIdx.x;
    const int lane = tid & 63;
    const int wave = tid >> 6;
    const int wm = (wave >> 1) * 64;
    const int wn = (wave & 1) * 64;
    const int fr = lane & 15;
    const int kq = lane >> 4;

    int srow[2], skq[2];
#pragma unroll
    for (int i = 0; i < 2; ++i) {
        const int s = i * 256 + tid;
        srow[i] = s >> 2;
        skq[i] = (s & 3) ^ ((s >> 3) & 3);
    }
    const int wslot = tid & 192;

    f32x4 acc[4][4];
#pragma unroll
    for (int i = 0; i < 4; ++i)
#pragma unroll
        for (int j = 0; j < 4; ++j)
#pragma unroll
            for (int r = 0; r < 4; ++r) acc[i][j][r] = 0.f;

    for (int k0 = 0; k0 < K; k0 += 32) {
        __syncthreads();
#pragma unroll
        for (int i = 0; i < 2; ++i) {
            const int sb = (i * 256 + wslot) * 8;
            gload16(Ab + (size_t)(bm + srow[i]) * K + k0 + skq[i] * 8, Ah + sb);
            gload16(Wb + (size_t)(bn + srow[i]) * K + k0 + skq[i] * 8, Bh + sb);
        }
        __syncthreads();

        bf16x8 fah[4], fbh[4];
#pragma unroll
        for (int mi = 0; mi < 4; ++mi) {
            const int rr = wm + mi * 16 + fr;
            fah[mi] = *reinterpret_cast<const bf16x8*>(
                Ah + (rr * 4 + (kq ^ ((rr >> 1) & 3))) * 8);
        }
#pragma unroll
        for (int ni = 0; ni < 4; ++ni) {
            const int rr = wn + ni * 16 + fr;
            fbh[ni] = *reinterpret_cast<const bf16x8*>(
                Bh + (rr * 4 + (kq ^ ((rr >> 1) & 3))) * 8);
        }

#pragma unroll
        for (int mi = 0; mi < 4; ++mi)
#pragma unroll
            for (int ni = 0; ni < 4; ++ni)
                acc[mi][ni] = __builtin_amdgcn_mfma_f32_16x16x32_bf16(
                    fah[mi], fbh[ni], acc[mi][ni], 0, 0, 0);
    }

    const int fq = lane >> 4;
    if (omode == 2) {          // bf16 out, ROW bias (swapped V^T GEMM)
#pragma unroll
        for (int mi = 0; mi < 4; ++mi)
#pragma unroll
            for (int r = 0; r < 4; ++r) {
                const int row = bm + wm + mi * 16 + fq * 4 + r;
                const float bvr = bias[row];
#pragma unroll
                for (int ni = 0; ni < 4; ++ni)
                    outB[(size_t)row * N + bn + wn + ni * 16 + fr] =
                        f32_to_bf16_rn((acc[mi][ni][r] + bvr) * oscale);
            }
    } else {
        float bv[4];
#pragma unroll
        for (int ni = 0; ni < 4; ++ni) bv[ni] = bias[bn + wn + ni * 16 + fr];
#pragma unroll
        for (int mi = 0; mi < 4; ++mi)
#pragma unroll
            for (int ni = 0; ni < 4; ++ni) {
                const size_t rowb = (size_t)(bm + wm + mi * 16 + fq * 4);
                const int col = bn + wn + ni * 16 + fr;
#pragma unroll
                for (int r = 0; r < 4; ++r) {
                    float v = (acc[mi][ni][r] + bv[ni]) * oscale;
                    if (omode == 0) outF[(rowb + r) * N + col] = v;
                    else            outB[(rowb + r) * N + col] = f32_to_bf16_rn(v);
                }
            }
    }
}

// ---------------------------------------------------------------------------
// fused Q/K/V^T projections with XCD-affinity swizzle (R20, unchanged)
// ---------------------------------------------------------------------------
__global__ __launch_bounds__(256) void proj_fused(
    const ushort_t* __restrict__ Qbf, const ushort_t* __restrict__ Kc,
    const ushort_t* __restrict__ Wvb, const ushort_t* __restrict__ Vc,
    const ushort_t* __restrict__ Wqb, const ushort_t* __restrict__ Wkb,
    const float* __restrict__ bq, const float* __restrict__ bk,
    const float* __restrict__ bv, const int* __restrict__ npads,
    ushort_t* __restrict__ Qb, ushort_t* __restrict__ Kb,
    ushort_t* __restrict__ Vtg, float sc2)
{
    __shared__ __align__(16) ushort_t Ah[128 * 32];
    __shared__ __align__(16) ushort_t Bh[128 * 32];

    int id = blockIdx.x;
    if (id < 512) {
        const int bm = (((id >> 6) << 3) | (id & 7)) * 128;
        const int bn = ((id >> 3) & 7) * 128;
        gemm_core(Qbf, Wqb, bq, Qb, nullptr, bm, bn, HID_C, HID_C, sc2, 1, Ah, Bh);
    } else if (id < 1024) {
        id -= 512;
        const int bm = (((id >> 6) << 3) | (id & 7)) * 128;
        const int bn = ((id >> 3) & 7) * 128;
        if ((bm & 2047) >= npads[bm >> 11]) return;
        gemm_core(Kc, Wkb, bk, Kb, nullptr, bm, bn, HID_C, HID_C, 1.f, 1, Ah, Bh);
    } else {
        id -= 1024;
        const int bn = (id & 63) * 128;
        if ((bn & 2047) >= npads[bn >> 11]) return;
        gemm_core(Wvb, Vc, bv, Vtg, nullptr, (id >> 6) * 128, bn,
                  4 * S_LEN, HID_C, 1.f, 2, Ah, Bh);
    }
}

// ---------------------------------------------------------------------------
// O-GEMM (R21): single bf16 A (X), 1 MFMA per fragment, fp32 out,
// XCD-affinity 1D decode.
// ---------------------------------------------------------------------------
__global__ __launch_bounds__(256) void gemm_out(
    const ushort_t* __restrict__ Xb, const ushort_t* __restrict__ Wb,
    const float* __restrict__ bias, float* __restrict__ outF,
    int M, int N, int K)
{
    __shared__ __align__(16) ushort_t Ah[128 * 32];
    __shared__ __align__(16) ushort_t Bh[128 * 32];

    const int n = blockIdx.x;
    const int bm = ((((n >> 6) << 3) | (n & 7))) * 128;
    const int bn = ((n >> 3) & 7) * 128;
    gemm_core(Xb, Wb, bias, nullptr, outF, bm, bn, N, K, 1.f, 0, Ah, Bh);
}

// ---------------------------------------------------------------------------
// Flash attention — R17 kernel; epilogue writes SINGLE bf16 X (R21).
// ---------------------------------------------------------------------------
#define QBLK 128
#define KVB  64
#define LDA  72

__global__ __launch_bounds__(256) void flash_attn_bf16(
    const ushort_t* __restrict__ Qb, const ushort_t* __restrict__ Kb,
    const ushort_t* __restrict__ Vtg, const float* __restrict__ maskb,
    const int* __restrict__ npads, ushort_t* __restrict__ Xb)
{
    __shared__ __align__(16) ushort_t Ks[KVB * LDA];
    __shared__ __align__(16) ushort_t Vt[HDIM * LDA];
    __shared__ float Xpose[QBLK];

    const int n  = blockIdx.x;
    const int bh = (n & 7) * 8 + ((n >> 3) & 7);
    const int qx = n >> 6;
    const int b  = bh >> 4;
    const int h  = bh & 15;
    const int q0 = qx * QBLK;

    const int tid  = threadIdx.x;
    const int lane = tid & 63;
    const int w    = tid >> 6;
    const int lq = lane & 31;
    const int lh = lane >> 5;

    const size_t bS = (size_t)b * S_LEN;
    const int hc = h * HDIM;
    const int npad = npads[b];

    bf16x8 qf[4];
#pragma unroll
    for (int s = 0; s < 4; ++s)
        qf[s] = *reinterpret_cast<const bf16x8*>(
            &Qb[(bS + q0 + w * 32 + lq) * HID_C + hc + s * 16 + lh * 8]);

    f32x16 OV[2], zc;
#pragma unroll
    for (int r = 0; r < 16; ++r) { OV[0][r] = 0.f; OV[1][r] = 0.f; zc[r] = 0.f; }
    float m_ = -1e30f, l_ = 0.f;

    const int sr  = tid >> 2;
    const int seg = tid & 3;
    const ushort_t* kbase = &Kb[(bS + sr) * HID_C + hc + seg * 16];
    const ushort_t* vbase = &Vtg[(size_t)(hc + sr) * (4 * S_LEN) + bS + seg * 16];

    {
        bf16x8 kv0 = *reinterpret_cast<const bf16x8*>(kbase);
        bf16x8 kv1 = *reinterpret_cast<const bf16x8*>(kbase + 8);
        bf16x8 vv0 = *reinterpret_cast<const bf16x8*>(vbase);
        bf16x8 vv1 = *reinterpret_cast<const bf16x8*>(vbase + 8);
        *reinterpret_cast<bf16x8*>(&Ks[sr * LDA + seg * 16])     = kv0;
        *reinterpret_cast<bf16x8*>(&Ks[sr * LDA + seg * 16 + 8]) = kv1;
        *reinterpret_cast<bf16x8*>(&Vt[sr * LDA + seg * 16])     = vv0;
        *reinterpret_cast<bf16x8*>(&Vt[sr * LDA + seg * 16 + 8]) = vv1;
        __syncthreads();
    }

    for (int t = 0; t < npad; t += KVB) {
        // ---- QK^T (swapped, 32x32x16), zero-C first MFMA ----
        f32x16 S[2];
        __builtin_amdgcn_s_setprio(1);
#pragma unroll
        for (int kt = 0; kt < 2; ++kt) {
            bf16x8 kf0 = *reinterpret_cast<const bf16x8*>(
                &Ks[(kt * 32 + lq) * LDA + lh * 8]);
            S[kt] = __builtin_amdgcn_mfma_f32_32x32x16_bf16(kf0, qf[0], zc, 0, 0, 0);
#pragma unroll
            for (int s = 1; s < 4; ++s) {
                bf16x8 kf = *reinterpret_cast<const bf16x8*>(
                    &Ks[(kt * 32 + lq) * LDA + s * 16 + lh * 8]);
                S[kt] = __builtin_amdgcn_mfma_f32_32x32x16_bf16(
                    kf, qf[s], S[kt], 0, 0, 0);
            }
        }
        __builtin_amdgcn_s_setprio(0);

        // ---- T14: issue next-tile K/V loads ----
        const bool more = (t + KVB < npad);
        bf16x8 kv0n, kv1n, vv0n, vv1n;
        if (more) {
            const ushort_t* kp = kbase + (size_t)(t + KVB) * HID_C;
            const ushort_t* vp = vbase + (t + KVB);
            kv0n = *reinterpret_cast<const bf16x8*>(kp);
            kv1n = *reinterpret_cast<const bf16x8*>(kp + 8);
            vv0n = *reinterpret_cast<const bf16x8*>(vp);
            vv1n = *reinterpret_cast<const bf16x8*>(vp + 8);
        }

        // ---- mask bias: only the FINAL tile can contain padded keys ----
        if (!more) {
#pragma unroll
            for (int kt = 0; kt < 2; ++kt)
#pragma unroll
                for (int g = 0; g < 4; ++g) {
                    float4 mv = *reinterpret_cast<const float4*>(
                        &maskb[bS + t + kt * 32 + g * 8 + lh * 4]);
#pragma unroll
                    for (int e = 0; e < 4; ++e)
                        S[kt][g * 4 + e] += reinterpret_cast<const float*>(&mv)[e];
                }
        }

        // ---- tree row-max (one q per lane) ----
        float mx = fmaxf(tmax16(S[0]), tmax16(S[1]));
        mx = fmaxf(mx, __shfl_xor(mx, 32));

        // ---- defer-max (rare rescale) ----
        if (!__all(mx <= m_ + 8.f)) {
            float mn = fmaxf(m_, mx);
            float corr = fexp2(m_ - mn);
            m_ = mn; l_ *= corr;
            if (lh == 0) Xpose[w * 32 + lq] = corr;   // same-wave RAW
#pragma unroll
            for (int r = 0; r < 16; ++r) {
                float cq = Xpose[w * 32 + (r & 3) + 8 * (r >> 2) + 4 * lh];
                OV[0][r] *= cq;
                OV[1][r] *= cq;
            }
        }

        // ---- P = exp2(S - m) via raw v_exp_f32, tree row-sum ----
#pragma unroll
        for (int kt = 0; kt < 2; ++kt)
#pragma unroll
            for (int r = 0; r < 16; ++r) S[kt][r] = fexp2(S[kt][r] - m_);
        float ls = tsum16(S[0]) + tsum16(S[1]);
        ls += __shfl_xor(ls, 32);
        l_ += ls;

        // ---- P -> PV A-frags in registers (cvt_pk + permlane32_swap) ----
        bf16x8 pa[4];
#pragma unroll
        for (int kt = 0; kt < 2; ++kt)
#pragma unroll
            for (int u = 0; u < 2; ++u) {
                const int bb = u * 8;
                unsigned int c0, c1, c2, c3;
                asm("v_cvt_pk_bf16_f32 %0, %1, %2"
                    : "=v"(c0) : "v"(S[kt][bb + 0]), "v"(S[kt][bb + 1]));
                asm("v_cvt_pk_bf16_f32 %0, %1, %2"
                    : "=v"(c1) : "v"(S[kt][bb + 2]), "v"(S[kt][bb + 3]));
                asm("v_cvt_pk_bf16_f32 %0, %1, %2"
                    : "=v"(c2) : "v"(S[kt][bb + 4]), "v"(S[kt][bb + 5]));
                asm("v_cvt_pk_bf16_f32 %0, %1, %2"
                    : "=v"(c3) : "v"(S[kt][bb + 6]), "v"(S[kt][bb + 7]));
                asm("v_permlane32_swap_b32 %0, %1" : "+v"(c0), "+v"(c2));
                asm("v_permlane32_swap_b32 %0, %1" : "+v"(c1), "+v"(c3));
                uint4 wv = make_uint4(c0, c1, c2, c3);
                pa[kt * 2 + u] = *reinterpret_cast<bf16x8*>(&wv);
            }

        // ---- PV (32x32x16) ----
        __builtin_amdgcn_s_setprio(1);
#pragma unroll
        for (int dt = 0; dt < 2; ++dt)
#pragma unroll
            for (int f = 0; f < 4; ++f) {
                bf16x8 vf = *reinterpret_cast<const bf16x8*>(
                    &Vt[(dt * 32 + lq) * LDA + f * 16 + lh * 8]);
                OV[dt] = __builtin_amdgcn_mfma_f32_32x32x16_bf16(
                    pa[f], vf, OV[dt], 0, 0, 0);
            }
        __builtin_amdgcn_s_setprio(0);

        // ---- stage next tile ----
        __syncthreads();
        if (more) {
            *reinterpret_cast<bf16x8*>(&Ks[sr * LDA + seg * 16])     = kv0n;
            *reinterpret_cast<bf16x8*>(&Ks[sr * LDA + seg * 16 + 8]) = kv1n;
            *reinterpret_cast<bf16x8*>(&Vt[sr * LDA + seg * 16])     = vv0n;
            *reinterpret_cast<bf16x8*>(&Vt[sr * LDA + seg * 16 + 8]) = vv1n;
            __syncthreads();
        }
    }

    // ---- epilogue: x = OV/l, single bf16 write (R21) ----
    if (lh == 0) Xpose[w * 32 + lq] = 1.f / l_;   // same-wave RAW
#pragma unroll
    for (int r = 0; r < 16; ++r) {
        const int qr = (r & 3) + 8 * (r >> 2) + 4 * lh;
        const float inv = Xpose[w * 32 + qr];
        const size_t row = bS + q0 + w * 32 + qr;
#pragma unroll
        for (int dt = 0; dt < 2; ++dt)
            Xb[row * HID_C + hc + dt * 32 + lq] = f32_to_bf16_rn(OV[dt][r] * inv);
    }
}

// ---------------------------------------------------------------------------
extern "C" void kernel_launch(void* const* d_in, const int* in_sizes, int n_in,
                              void* d_out, int out_size, void* d_ws, size_t ws_size,
                              hipStream_t stream) {
    const float* query = (const float*)d_in[0];
    const float* key   = (const float*)d_in[1];
    const float* value = (const float*)d_in[2];
    const int*   mask  = (const int*)d_in[3];
    const float* Wq = (const float*)d_in[4];
    const float* bq = (const float*)d_in[5];
    const float* Wk = (const float*)d_in[6];
    const float* bk = (const float*)d_in[7];
    const float* Wv = (const float*)d_in[8];
    const float* bv = (const float*)d_in[9];
    const float* Wo = (const float*)d_in[10];
    const float* bo = (const float*)d_in[11];
    float* out = (float*)d_out;

    const int B = 4, M = B * S_LEN;          // 8192
    const size_t seg = (size_t)M * HID_C;
    const size_t nw  = (size_t)HID_C * HID_C;

    ushort_t* Qb  = (ushort_t*)d_ws;         // 16MB each
    ushort_t* Kb  = Qb + seg;
    ushort_t* Vtg = Kb + seg;                // V^T: [1024 feat][8192 compact tok]
    ushort_t* Xb  = Vtg + seg;               // aliased: Kc before attn
    ushort_t* Vc  = Xb + seg;                // compact bf16 value rows
    ushort_t* Qbf = Vc + seg;                // query bf16
    float*    Mbc = (float*)(Qbf + seg);     // 32KB compact mask bias
    ushort_t* Wqb = (ushort_t*)(Mbc + 4 * S_LEN);
    ushort_t* Wkb = Wqb + nw;                // 2MB each
    ushort_t* Wob = Wkb + nw;
    ushort_t* Wvb = Wob + nw;
    int*      cidx   = (int*)(Wvb + nw);     // 32KB
    int*      nvalid = cidx + 4 * S_LEN;
    int*      npads  = nvalid + 4;           // total ~105MB

    ushort_t* Kc = Xb;                       // compact bf16 key rows (pre-attn)

    scan_mask<<<dim3(4), 64, 0, stream>>>(mask, cidx, nvalid, npads);
    prep_gather<<<dim3(CONVB + M), 256, 0, stream>>>(
        query, Wq, Wk, Wo, Wv, key, value, cidx, nvalid,
        Qbf, Wqb, Wkb, Wob, Wvb, Kc, Vc, Mbc);

    const float SC2 = 0.125f * LOG2E;
    proj_fused<<<dim3(1536), 256, 0, stream>>>(
        Qbf, Kc, Wvb, Vc, Wqb, Wkb, bq, bk, bv, npads, Qb, Kb, Vtg, SC2);

    flash_attn_bf16<<<dim3((S_LEN / QBLK) * B * NHEADS), 256, 0, stream>>>(
        Qb, Kb, Vtg, Mbc, npads, Xb);

    gemm_out<<<dim3(512), 256, 0, stream>>>(
        Xb, Wob, bo, out, M, HID_C, HID_C);
}